// Round 6
// baseline (667.067 us; speedup 1.0000x reference)
//
#include <hip/hip_runtime.h>
#include <stdint.h>

// Problem constants
#define BATCH 2
#define CIN 128
#define COUT 512
#define DD 8
#define PSPAT 8192          // D*H*W
#define NA 9                // anchors per position
#define NANCH 73728         // PSPAT*NA
#define PRE 2048
#define POST 300
#define CAP 4096            // candidate buffer (top-2048 + cutoff-bin ties)
#define NMS_TH 0.7f

typedef unsigned short u16;
typedef _Float16 f16x8 __attribute__((ext_vector_type(8)));
typedef float f32x16 __attribute__((ext_vector_type(16)));
typedef unsigned int uint32x4 __attribute__((ext_vector_type(4)));

// ws layout (byte offsets). Base footprint = proven 46,104,576 B.
// R18 == R17 with the macro-arity compile fix (token-pasting frag macros).
// Acts' f16 hi/lo split PRECOMPUTED by k_split into xh/xl planes ABOVE the
// base footprint (needs ws >= 54,493,184 B). Runtime-gated on ws_size: if
// too small, fall back to the R16 in-kernel-split k_conv (bit-identical
// numerics either way). R16 diagnosis: VALUBusy 44% vs MfmaUtil 22.5% — the
// per-stage 64 scalar loads (unfoldable 32KB strides) + ~350 cvt ops, done
// 8x redundantly per act value, are the critical pipe. k_conv_f loads frags
// as 16 x dwordx4 with zero cvt VALU.
constexpr size_t OFF_WT   = 0;          // 108*2 blocks * 32KB = 7,077,888 B (f16 hi/lo image)
constexpr size_t OFF_WHT  = 7077888;    // 512*80 f32       = 163,840 B
constexpr size_t OFF_X    = 7241728;    // 2*512*8192 f32   = 33,554,432 B
constexpr size_t OFF_SC   = 40796160;   // 2*73728 f32      = 589,824 B
constexpr size_t OFF_BX   = 41385984;   // 2*73728*6 f32    = 3,538,944 B
constexpr size_t OFF_SB   = 44957696;   // 2*2048*6 f32     = 98,304 B
constexpr size_t OFF_MK   = 45056000;   // 2*2048*32 u64    = 1,048,576 B  (end 46,104,576)
// selection scratch inside [0, OFF_WT+7MB), used only after k_conv:
constexpr size_t OFF_HIST = 16;              // 2*65536 u32 = 524,288 B
constexpr size_t OFF_CAND = 524304;          // 2*4096 u64  = 65,536 B
// fast-path act planes (only if ws_size >= WS_NEED_FAST):
constexpr size_t OFF_XH   = 46104576;   // [b][d][h][w][ci] f16 = 4,194,304 B
constexpr size_t OFF_XL   = 50298880;   // 4,194,304 B
constexpr size_t WS_NEED_FAST = 54493184;

// ---------------- fused weight transforms (one launch) ----------------
// Wg: per (nt,tap,cihalf): 32 KB block = 128 rows (local cout) x 256 B.
// Row n holds 64 hi f16 then 64 lo f16, as 16 columns of 16 B, stored
// column = logical ^ (n&15) (4-bit XOR swizzle; bijective). EXACT LDS image
// k_conv wants -> global_load_lds copies linearly (pre-swizzled-source,
// m173); ds_read_b128 frag reads measured 0 bank conflicts (R15/R16).
// f16 split with x1024 scale: wh+wl = 1024*w, residual floor ~2^-22 rel.
#define NT_WT   (27 * 128 * 512)
#define NT_WHT  (512 * 80)
__global__ void k_wtrans(const float* __restrict__ Wc, u16* __restrict__ Wg,
                         const float* __restrict__ Wcls, const float* __restrict__ Wbb,
                         float* __restrict__ Wht) {
    int e = blockIdx.x * blockDim.x + threadIdx.x;
    if (e < NT_WT) {
        const int k    = e & 63;
        const int n    = (e >> 6) & 127;
        const int half = (e >> 13) & 1;
        const int rest = e >> 14;            // nt*27 + tap, [0,108)
        const int co = (rest / 27) * 128 + n;
        const int ci = half * 64 + k;
        const int tp = rest % 27;
        const float v = Wc[(co * 128 + ci) * 27 + tp] * 1024.f;
        const _Float16 h = (_Float16)v;
        const _Float16 l = (_Float16)(v - (float)h);
        char* rb = (char*)Wg + (((size_t)(rest * 2 + half)) << 15) + n * 256;
        const int hcol = (k >> 3) ^ (n & 15);
        const int lcol = ((k >> 3) | 8) ^ (n & 15);
        const int kb = (k & 7) << 1;
        *(u16*)(rb + (hcol << 4) + kb) = __builtin_bit_cast(unsigned short, h);
        *(u16*)(rb + (lcol << 4) + kb) = __builtin_bit_cast(unsigned short, l);
        return;
    }
    e -= NT_WT;
    if (e >= NT_WHT) return;
    int q = e % 80;
    int c = e / 80;
    int og = q / 10, k = q % 10;
    int o = og * 9 + k;
    float v = 0.f;
    if (k < 9) v = (o < 18) ? Wcls[o * 512 + c] : Wbb[(o - 18) * 512 + c];
    Wht[e] = v;
}

// ---------------- input transpose + f16 hi/lo split (fast path only) ----------------
// base_feat [b][128ci][8][32][32] f32 -> xh/xl [b][8][32][32][128ci] f16.
// Values: h = f16(1024*a), l = f16(1024*a - h) — BIT-IDENTICAL to the
// in-kernel split of R14/R15/R16 (same formula, same rounding).
__global__ __launch_bounds__(256) void k_split(const float* __restrict__ in,
                                               u16* __restrict__ xh, u16* __restrict__ xl) {
    __shared__ float t[128][33];
    const int blk = blockIdx.x;                  // b*256 + d*32 + h
    const int b = blk >> 8, d = (blk >> 5) & 7, h = blk & 31;
    const int tid = threadIdx.x;
    const float* src = in + ((size_t)b << 20) + d * 1024 + h * 32;
    #pragma unroll
    for (int i = 0; i < 16; ++i) {
        const int e = tid + i * 256;
        const int ci = e >> 5, w = e & 31;
        t[ci][w] = src[(size_t)ci * 8192 + w];
    }
    __syncthreads();
    const size_t ob = (size_t)((b * 8 + d) * 32 + h) * 4096;   // *32w*128ci
    #pragma unroll
    for (int i = 0; i < 16; ++i) {
        const int e = tid + i * 256;
        const int w = e >> 7, ci = e & 127;
        const float v = t[ci][w] * 1024.f;
        const _Float16 hh = (_Float16)v;
        const _Float16 ll = (_Float16)(v - (float)hh);
        xh[ob + w * 128 + ci] = __builtin_bit_cast(unsigned short, hh);
        xl[ob + w * 128 + ci] = __builtin_bit_cast(unsigned short, ll);
    }
}

// ---------------- conv3d 3x3x3 + bias + relu: MFMA implicit GEMM ----------------
// Shared pieces (both conv variants): MFMA core, W staging, epilogue.
#define MFMA(A, B, C) __builtin_amdgcn_mfma_f32_32x32x16_f16((A), (B), (C), 0, 0, 0)
#define Z16 {0.f,0.f,0.f,0.f,0.f,0.f,0.f,0.f,0.f,0.f,0.f,0.f,0.f,0.f,0.f,0.f}

// Stage S weights (32 KB) -> LDS buffer BUF via global_load_lds, linear copy.
#define WISSUE(S, BUF) { \
    const int tap_ = t0 + ((S) >> 1); \
    const char* gw_ = WgB + (((size_t)((nt * 27 + tap_) * 2 + ((S) & 1))) << 15) \
                    + (wv << 13) + ln16; \
    char* lb_ = smem + ((BUF) << 15) + (wv << 13); \
    _Pragma("unroll") \
    for (int j_ = 0; j_ < 8; ++j_) \
        __builtin_amdgcn_global_load_lds( \
            (const __attribute__((address_space(1))) void*)(gw_ + (j_ << 10)), \
            (__attribute__((address_space(3))) void*)(lb_ + (j_ << 10)), 16, 0, 0); }

#define KKSTEP(KK, BH0, BL0, BH1, BL1) { \
    const int ch_ = ((((KK) << 1) + cq) ^ rsw) << 4; \
    const int cl_ = (((((KK) << 1) + cq) | 8) ^ rsw) << 4; \
    const char* r0_ = wb_ + (rm0 << 8); \
    const char* r1_ = wb_ + (rm1 << 8); \
    const f16x8 wh0 = *(const f16x8*)(r0_ + ch_); \
    const f16x8 wl0 = *(const f16x8*)(r0_ + cl_); \
    const f16x8 wh1 = *(const f16x8*)(r1_ + ch_); \
    const f16x8 wl1 = *(const f16x8*)(r1_ + cl_); \
    acc00 = MFMA(wh0, BH0, acc00); acc00 = MFMA(wh0, BL0, acc00); acc00 = MFMA(wl0, BH0, acc00); \
    acc01 = MFMA(wh0, BH1, acc01); acc01 = MFMA(wh0, BL1, acc01); acc01 = MFMA(wl0, BH1, acc01); \
    acc10 = MFMA(wh1, BH0, acc10); acc10 = MFMA(wh1, BL0, acc10); acc10 = MFMA(wl1, BH0, acc10); \
    acc11 = MFMA(wh1, BH1, acc11); acc11 = MFMA(wh1, BL1, acc11); acc11 = MFMA(wl1, BH1, acc11); }

// acc = 2^20 * conv -> unscale exactly, + bias, relu
#define EPI(ACC, MI, NI) { \
    const int coB_ = co0 + (wm << 6) + ((MI) << 5) + hl4; \
    const int pt_  = p0 + (wn << 6) + ((NI) << 5) + l31; \
    _Pragma("unroll") \
    for (int g_ = 0; g_ < 4; ++g_) { \
        _Pragma("unroll") \
        for (int q_ = 0; q_ < 4; ++q_) { \
            const int co_ = coB_ + (g_ << 3) + q_; \
            const float v_ = ACC[g_ * 4 + q_] * 9.5367431640625e-07f + bconv[co_]; \
            x[((size_t)((b << 9) + co_) << 13) + pt_] = fmaxf(v_, 0.f); \
        } } }

// ======== FAST conv: acts pre-split, B-frags = direct 16B loads ========
// One frag pair (N,KK): two dwordx4 loads; KK*32B folds into inst offset.
// Halo: h/w clamped IN-PLANE for the address (&31), value zeroed by cndmask.
// P is a fragment-set prefix token (A or B); P##h00 etc. are named VGPR vars.
#define FLD(N, KK, BH, BL) { \
    const int h2_ = hb_ + (N); \
    const bool ok_ = okw_ && ((unsigned)h2_ < 32u); \
    const size_t ix_ = sbase_ + ((size_t)((h2_ & 31) << 5) << 7); \
    const f16x8 vh_ = *(const f16x8*)(xh + ix_ + ((KK) << 4)); \
    const f16x8 vl_ = *(const f16x8*)(xl + ix_ + ((KK) << 4)); \
    BH = ok_ ? vh_ : fz8; \
    BL = ok_ ? vl_ : fz8; }

#define ALOADF(S, P) { \
    const int tap_ = t0 + ((S) >> 1); \
    const int kd_ = tap_ / 9, kh_ = (tap_ / 3) % 3, kw_ = tap_ % 3; \
    const int id_ = d0 + kd_ - 1; \
    const int w2_ = l31 + kw_ - 1; \
    const bool okw_ = (unsigned)w2_ < 32u; \
    const int hb_ = h0 + (wn << 1) + kh_ - 1; \
    const int cio_ = (((S) & 1) << 6) + (cq << 3); \
    const size_t sbase_ = (((size_t)((b << 3) + id_)) << 17) + ((w2_ & 31) << 7) + cio_; \
    FLD(0, 0, P##h00, P##l00) FLD(0, 1, P##h01, P##l01) \
    FLD(0, 2, P##h02, P##l02) FLD(0, 3, P##h03, P##l03) \
    FLD(1, 0, P##h10, P##l10) FLD(1, 1, P##h11, P##l11) \
    FLD(1, 2, P##h12, P##l12) FLD(1, 3, P##h13, P##l13) }

#define COMPUTEF(BUF, P) { \
    const char* wb_ = smem + ((BUF) << 15); \
    KKSTEP(0, P##h00, P##l00, P##h10, P##l10) \
    KKSTEP(1, P##h01, P##l01, P##h11, P##l11) \
    KKSTEP(2, P##h02, P##l02, P##h12, P##l12) \
    KKSTEP(3, P##h03, P##l03, P##h13, P##l13) }

__global__ __launch_bounds__(256, 2) void k_conv_f(const u16* __restrict__ xh,
                                                   const u16* __restrict__ xl,
                                                   const u16* __restrict__ Wg,
                                                   const float* __restrict__ bconv,
                                                   float* __restrict__ x) {
    __shared__ __align__(16) char smem[65536];   // W double-buffer: 2 x 32 KB
    const int tid  = threadIdx.x;
    const int bx   = blockIdx.x;        // 64 spatial tiles (128 pts each)
    const int nt   = blockIdx.y;        // 4 cout tiles of 128
    const int b    = blockIdx.z;
    const int p0   = bx << 7;
    const int d0   = bx >> 3;
    const int h0   = (bx & 7) << 2;
    const int co0  = nt << 7;

    const int lane = tid & 63;
    const int wv   = tid >> 6;          // wave id
    const int wm   = wv & 1;            // cout 64-half
    const int wn   = wv >> 1;           // pt 64-half
    const int l31  = lane & 31;         // frag row/col
    const int cq   = lane >> 5;         // frag k-octet half
    const int hl4  = cq << 2;           // C/D row group
    const int rsw  = l31 & 15;          // W-row XOR swizzle key
    const int rm0  = (wm << 6) + l31;   // weight LDS rows (256 B each)
    const int rm1  = rm0 + 32;
    const int ln16 = lane << 4;

    const int t0   = (d0 == 0) ? 9 : 0;
    const int nTap = 27 - (((d0 == 0) || (d0 == 7)) ? 9 : 0);
    const int NS   = nTap * 2;          // stages (EVEN: 54 or 36)

    const char* WgB = (const char*)Wg;
    const f16x8 fz8 = {(_Float16)0.f, (_Float16)0.f, (_Float16)0.f, (_Float16)0.f,
                       (_Float16)0.f, (_Float16)0.f, (_Float16)0.f, (_Float16)0.f};

    f16x8 Ah00, Al00, Ah01, Al01, Ah02, Al02, Ah03, Al03,
          Ah10, Al10, Ah11, Al11, Ah12, Al12, Ah13, Al13;
    f16x8 Bh00, Bl00, Bh01, Bl01, Bh02, Bl02, Bh03, Bl03,
          Bh10, Bl10, Bh11, Bl11, Bh12, Bl12, Bh13, Bl13;
    f32x16 acc00 = Z16, acc01 = Z16, acc10 = Z16, acc11 = Z16;

    WISSUE(0, 0)
    ALOADF(0, A)                        // prologue acts for stage 0
    __syncthreads();                    // drain prologue W staging

    for (int s = 0; s < NS; s += 2) {   // NS even; s+1 always valid
        // even stage s: consume A, prefetch (s+1) into B + alt W buf
        WISSUE(s + 1, 1)
        ALOADF(s + 1, B)
        __builtin_amdgcn_sched_barrier(0);
        COMPUTEF(0, A)
        __syncthreads();
        // odd stage s+1: consume B, prefetch (s+2) into A + buf 0
        if (s + 2 < NS) { WISSUE(s + 2, 0) ALOADF(s + 2, A) }
        __builtin_amdgcn_sched_barrier(0);
        COMPUTEF(1, B)
        __syncthreads();
    }

    EPI(acc00, 0, 0)
    EPI(acc01, 0, 1)
    EPI(acc10, 1, 0)
    EPI(acc11, 1, 1)
}

// ======== FALLBACK conv (exact R16): in-kernel split, pipelined ========
#define PK2(YA, YB, UH, UL) { \
    const float sa_ = (YA) * 1024.f, sb_ = (YB) * 1024.f; \
    const _Float16 ha_ = (_Float16)sa_, hb_ = (_Float16)sb_; \
    const _Float16 la_ = (_Float16)(sa_ - (float)ha_); \
    const _Float16 lb_ = (_Float16)(sb_ - (float)hb_); \
    UH = (unsigned)__builtin_bit_cast(unsigned short, ha_) | \
         ((unsigned)__builtin_bit_cast(unsigned short, hb_) << 16); \
    UL = (unsigned)__builtin_bit_cast(unsigned short, la_) | \
         ((unsigned)__builtin_bit_cast(unsigned short, lb_) << 16); }

#define BLDI(N, KK) { \
    const int h2_ = hb_ + (N); \
    const bool ok_ = okw_ && ((unsigned)h2_ < 32u); \
    const float* ap_ = in + (((size_t)(cb0_ + ((KK) << 4))) << 13) + spo_ + (h2_ << 5); \
    y[N][KK][0] = ok_ ? ap_[0]     : 0.f; \
    y[N][KK][1] = ok_ ? ap_[8192]  : 0.f; \
    y[N][KK][2] = ok_ ? ap_[16384] : 0.f; \
    y[N][KK][3] = ok_ ? ap_[24576] : 0.f; \
    y[N][KK][4] = ok_ ? ap_[32768] : 0.f; \
    y[N][KK][5] = ok_ ? ap_[40960] : 0.f; \
    y[N][KK][6] = ok_ ? ap_[49152] : 0.f; \
    y[N][KK][7] = ok_ ? ap_[57344] : 0.f; }

#define ALOADISS(S) { \
    const int tap_ = t0 + ((S) >> 1); \
    const int kd_ = tap_ / 9, kh_ = (tap_ / 3) % 3, kw_ = tap_ % 3; \
    const int id_ = d0 + kd_ - 1; \
    const int w2_ = l31 + kw_ - 1; \
    const bool okw_ = (unsigned)w2_ < 32u; \
    const int hb_ = h0 + (wn << 1) + kh_ - 1; \
    const int cb0_ = b * CIN + (((S) & 1) << 6) + (cq << 3); \
    const long long spo_ = ((long long)id_ << 10) + w2_; \
    BLDI(0, 0) BLDI(0, 1) BLDI(0, 2) BLDI(0, 3) \
    BLDI(1, 0) BLDI(1, 1) BLDI(1, 2) BLDI(1, 3) }

#define CVTFRAG(N, KK, BH, BL) { \
    unsigned uh0_, uh1_, uh2_, uh3_, ul0_, ul1_, ul2_, ul3_; \
    PK2(y[N][KK][0], y[N][KK][1], uh0_, ul0_) \
    PK2(y[N][KK][2], y[N][KK][3], uh1_, ul1_) \
    PK2(y[N][KK][4], y[N][KK][5], uh2_, ul2_) \
    PK2(y[N][KK][6], y[N][KK][7], uh3_, ul3_) \
    { uint32x4 th_ = {uh0_, uh1_, uh2_, uh3_}; BH = __builtin_bit_cast(f16x8, th_); } \
    { uint32x4 tl_ = {ul0_, ul1_, ul2_, ul3_}; BL = __builtin_bit_cast(f16x8, tl_); } }

#define CVTALL() { \
    CVTFRAG(0, 0, bh00, bl00) CVTFRAG(0, 1, bh01, bl01) \
    CVTFRAG(0, 2, bh02, bl02) CVTFRAG(0, 3, bh03, bl03) \
    CVTFRAG(1, 0, bh10, bl10) CVTFRAG(1, 1, bh11, bl11) \
    CVTFRAG(1, 2, bh12, bl12) CVTFRAG(1, 3, bh13, bl13) }

#define COMPUTE(BUF) { \
    const char* wb_ = smem + ((BUF) << 15); \
    KKSTEP(0, bh00, bl00, bh10, bl10) \
    KKSTEP(1, bh01, bl01, bh11, bl11) \
    KKSTEP(2, bh02, bl02, bh12, bl12) \
    KKSTEP(3, bh03, bl03, bh13, bl13) }

__global__ __launch_bounds__(256, 2) void k_conv(const float* __restrict__ in,
                                                 const u16* __restrict__ Wg,
                                                 const float* __restrict__ bconv,
                                                 float* __restrict__ x) {
    __shared__ __align__(16) char smem[65536];   // W double-buffer: 2 x 32 KB
    const int tid  = threadIdx.x;
    const int bx   = blockIdx.x;
    const int nt   = blockIdx.y;
    const int b    = blockIdx.z;
    const int p0   = bx << 7;
    const int d0   = bx >> 3;
    const int h0   = (bx & 7) << 2;
    const int co0  = nt << 7;

    const int lane = tid & 63;
    const int wv   = tid >> 6;
    const int wm   = wv & 1;
    const int wn   = wv >> 1;
    const int l31  = lane & 31;
    const int cq   = lane >> 5;
    const int hl4  = cq << 2;
    const int rsw  = l31 & 15;
    const int rm0  = (wm << 6) + l31;
    const int rm1  = rm0 + 32;
    const int ln16 = lane << 4;

    const int t0   = (d0 == 0) ? 9 : 0;
    const int nTap = 27 - (((d0 == 0) || (d0 == 7)) ? 9 : 0);
    const int NS   = nTap * 2;

    const char* WgB = (const char*)Wg;

    float y[2][4][8];
    f16x8 bh00, bh01, bh02, bh03, bh10, bh11, bh12, bh13;
    f16x8 bl00, bl01, bl02, bl03, bl10, bl11, bl12, bl13;
    f32x16 acc00 = Z16, acc01 = Z16, acc10 = Z16, acc11 = Z16;

    WISSUE(0, 0)
    ALOADISS(0)
    __syncthreads();

    for (int s = 0; s < NS; ++s) {
        if (s + 1 < NS) { WISSUE(s + 1, (s + 1) & 1) }
        CVTALL()
        __builtin_amdgcn_sched_barrier(0);
        if (s + 1 < NS) { ALOADISS(s + 1) }
        __builtin_amdgcn_sched_barrier(0);
        COMPUTE(s & 1)
        __syncthreads();
    }

    EPI(acc00, 0, 0)
    EPI(acc01, 0, 1)
    EPI(acc10, 1, 0)
    EPI(acc11, 1, 1)
}

// ---------------- heads GEMM + score/box epilogue + fused score histogram ----------------
// R12 form (measured best): unchanged.
__global__ __launch_bounds__(256) void k_heads(const float* __restrict__ x,
                                               const float* __restrict__ Wht,
                                               const float* __restrict__ bcls,
                                               const float* __restrict__ bbb,
                                               const float* __restrict__ iminfo,
                                               float* __restrict__ scores,
                                               float* __restrict__ boxes,
                                               unsigned int* __restrict__ hist) {
    __shared__ __align__(16) float smx[4096];    // x chunk [ch32][pt128]  16 KB
    __shared__ __align__(16) float Whs[2560];    // weight chunk [kk32][80] 10 KB
    __shared__ __align__(16) float ex[10240];    // exchange [pt128][80]    40 KB
    const int tid = threadIdx.x;
    const int p0  = blockIdx.x * 128;
    const int b   = blockIdx.y;
    const int pl  = tid & 31;     // 32 point-lanes, 4 consecutive points each
    const int og  = tid >> 5;     // 8 output groups of 9

    float acc[4][9] = {};

    for (int cc = 0; cc < 512; cc += 32) {
        __syncthreads();
        #pragma unroll
        for (int i = 0; i < 4; ++i) {
            int e4 = tid + i * 256;          // 1024 float4s
            int ch = e4 >> 5;
            int pt4 = (e4 & 31) * 4;
            *(float4*)&smx[ch * 128 + pt4] =
                *(const float4*)&x[((size_t)(b * COUT + cc + ch) << 13) + p0 + pt4];
        }
        #pragma unroll
        for (int i = 0; i < 10; ++i) {
            int e = tid + i * 256;
            Whs[e] = Wht[cc * 80 + e];
        }
        __syncthreads();
        for (int kk = 0; kk < 32; ++kk) {
            float4 a4 = *(const float4*)&smx[kk * 128 + pl * 4];
            const float* wp = &Whs[kk * 80 + og * 10];
            float2 w0 = *(const float2*)(wp);
            float2 w1 = *(const float2*)(wp + 2);
            float2 w2 = *(const float2*)(wp + 4);
            float2 w3 = *(const float2*)(wp + 6);
            float  w8 = wp[8];
            float wv[9] = {w0.x, w0.y, w1.x, w1.y, w2.x, w2.y, w3.x, w3.y, w8};
            #pragma unroll
            for (int k = 0; k < 9; ++k) {
                float wk = wv[k];
                acc[0][k] += a4.x * wk;
                acc[1][k] += a4.y * wk;
                acc[2][k] += a4.z * wk;
                acc[3][k] += a4.w * wk;
            }
        }
    }

    __syncthreads();
    #pragma unroll
    for (int pi = 0; pi < 4; ++pi)
        #pragma unroll
        for (int k = 0; k < 9; ++k)
            ex[(pl * 4 + pi) * 80 + og * 10 + k] = acc[pi][k];
    __syncthreads();

    if (tid < 128) {
        const int p = p0 + tid;
        float v[72];
        #pragma unroll
        for (int og2 = 0; og2 < 8; ++og2)
            #pragma unroll
            for (int k = 0; k < 9; ++k)
                v[og2 * 9 + k] = ex[tid * 80 + og2 * 10 + k];

        const float im0 = iminfo[b * 3 + 0], im1 = iminfo[b * 3 + 1], im2 = iminfo[b * 3 + 2];
        const float hix = im2 - 1.f, hiy = im1 - 1.f, hiz = im0 - 1.f;
        const int d = p >> 10, h = (p >> 5) & 31, w = p & 31;
        const float sx = w * 8.f, sy = h * 8.f, sz = d * 8.f;

        #pragma unroll 1
        for (int a = 0; a < 9; ++a) {
            float c0 = v[a] + bcls[a];
            float c1 = v[9 + a] + bcls[9 + a];
            float m  = fmaxf(c0, c1);
            float e0 = expf(c0 - m), e1 = expf(c1 - m);
            float sc = e1 / (e0 + e1);
            scores[b * NANCH + p * 9 + a] = sc;
            atomicAdd(&hist[b * 65536 + (__float_as_uint(sc) >> 16)], 1u);

            float aw = (float)(32 << (a % 3));                 // x,y size = 8*SCALES
            float ad = aw * 0.5f * (float)(1 << (a / 3));      // z size = aw*RATIOS
            float ax1 = sx + 3.5f - 0.5f * (aw - 1.f);
            float ax2 = sx + 3.5f + 0.5f * (aw - 1.f);
            float ay1 = sy + 3.5f - 0.5f * (aw - 1.f);
            float ay2 = sy + 3.5f + 0.5f * (aw - 1.f);
            float az1 = sz + 3.5f - 0.5f * (ad - 1.f);
            float az2 = sz + 3.5f + 0.5f * (ad - 1.f);
            float ww_ = ax2 - ax1 + 1.f, hh_ = ay2 - ay1 + 1.f, dd_ = az2 - az1 + 1.f;
            float cx = ax1 + 0.5f * ww_, cy = ay1 + 0.5f * hh_, cz = az1 + 0.5f * dd_;

            const float* dv = &v[18 + a * 6];
            float dx = dv[0] + bbb[a * 6 + 0];
            float dy = dv[1] + bbb[a * 6 + 1];
            float dz = dv[2] + bbb[a * 6 + 2];
            float dw = dv[3] + bbb[a * 6 + 3];
            float dh = dv[4] + bbb[a * 6 + 4];
            float dd2 = dv[5] + bbb[a * 6 + 5];
            float pcx = dx * ww_ + cx, pcy = dy * hh_ + cy, pcz = dz * dd_ + cz;
            float pw = expf(dw) * ww_, ph = expf(dh) * hh_, pd = expf(dd2) * dd_;
            float x1 = fminf(fmaxf(pcx - 0.5f * pw, 0.f), hix);
            float y1 = fminf(fmaxf(pcy - 0.5f * ph, 0.f), hiy);
            float z1 = fminf(fmaxf(pcz - 0.5f * pd, 0.f), hiz);
            float x2 = fminf(fmaxf(pcx + 0.5f * pw, 0.f), hix);
            float y2 = fminf(fmaxf(pcy + 0.5f * ph, 0.f), hiy);
            float z2 = fminf(fmaxf(pcz + 0.5f * pd, 0.f), hiz);
            float* bp = &boxes[(size_t)(b * NANCH + p * 9 + a) * 6];
            bp[0] = x1; bp[1] = y1; bp[2] = z1; bp[3] = x2; bp[4] = y2; bp[5] = z2;
        }
    }
}

// ---------------- fused cutoff + compact (one block per batch) ----------------
__global__ __launch_bounds__(1024) void k_cutcompact(const float* __restrict__ scores,
                                                     const unsigned int* __restrict__ hist,
                                                     unsigned long long* __restrict__ cand) {
    __shared__ unsigned int cs[1024], scan[1024];
    __shared__ unsigned int sh_cut, sh_pos;
    const int b = blockIdx.x, tid = threadIdx.x;
    const unsigned int* h = hist + b * 65536;
    unsigned int s = 0;
    for (int i = 0; i < 64; ++i) s += h[tid * 64 + i];
    cs[tid] = s; scan[tid] = s;
    if (tid == 0) sh_pos = 0;
    __syncthreads();
    for (int d = 1; d < 1024; d <<= 1) {           // scan[c] -> sum_{c'>=c} cs[c']
        unsigned int v = scan[tid];
        unsigned int add = (tid + d < 1024) ? scan[tid + d] : 0u;
        __syncthreads();
        scan[tid] = v + add;
        __syncthreads();
    }
    unsigned int above = (tid + 1 < 1024) ? scan[tid + 1] : 0u;   // strictly above this chunk
    if (above < PRE && above + cs[tid] >= PRE) {   // exactly one thread
        unsigned int cum = above;
        for (int x = tid * 64 + 63; x >= tid * 64; --x) {
            cum += h[x];
            if (cum >= PRE) { sh_cut = (unsigned int)x; break; }
        }
    }
    __syncthreads();
    const unsigned int cut = sh_cut;
    const float* sc = scores + b * NANCH;
    for (int i = tid; i < NANCH; i += 1024) {
        unsigned int u = __float_as_uint(sc[i]);
        if ((u >> 16) >= cut) {
            unsigned int pos = atomicAdd(&sh_pos, 1u);
            if (pos < CAP) cand[b * CAP + pos] = ((unsigned long long)(~u) << 32) | (unsigned)i;
        }
    }
    __syncthreads();
    const unsigned int cnt = (sh_pos < CAP) ? sh_pos : CAP;
    for (int i = (int)cnt + tid; i < CAP; i += 1024)
        cand[b * CAP + i] = ~0ull;
}

// bitonic sort CAP keys asc (key = ~score_bits || idx => score desc, idx asc);
// first 2048 are the sorted top-2048; gather their boxes.
__global__ __launch_bounds__(1024) void k_sort2(const unsigned long long* __restrict__ cand,
                                                const float* __restrict__ boxes,
                                                float* __restrict__ sboxes) {
    __shared__ unsigned long long sk[CAP];
    const int b = blockIdx.x, tid = threadIdx.x;
    for (int i = tid; i < CAP; i += 1024) sk[i] = cand[b * CAP + i];
    __syncthreads();
    for (int k = 2; k <= CAP; k <<= 1) {
        for (int j = k >> 1; j > 0; j >>= 1) {
            #pragma unroll 1
            for (int i = tid; i < CAP; i += 1024) {
                int ixj = i ^ j;
                if (ixj > i) {
                    unsigned long long va = sk[i], vb = sk[ixj];
                    bool up = ((i & k) == 0);
                    if ((va > vb) == up) { sk[i] = vb; sk[ixj] = va; }
                }
            }
            __syncthreads();
        }
    }
    for (int r = tid; r < PRE; r += 1024) {
        unsigned int n = (unsigned int)(sk[r] & 0xFFFFFFFFull);
        const float* src = &boxes[(size_t)(b * NANCH + (int)n) * 6];
        float* dst = &sboxes[(size_t)(b * PRE + r) * 6];
        #pragma unroll
        for (int c = 0; c < 6; ++c) dst[c] = src[c];
    }
}

// suppression bitmask (upper triangle only): mask[b][i][w] bit j <=> j>i && IoU>0.7
__global__ __launch_bounds__(256) void k_mask(const float* __restrict__ sboxes,
                                              unsigned long long* __restrict__ mask) {
    if (blockIdx.y < blockIdx.x) return;   // j0 < i0: never read (k_nms gates by word)
    __shared__ float rb[64 * 6], cb[64 * 6];
    const int i0 = blockIdx.x * 64, j0 = blockIdx.y * 64, b = blockIdx.z;
    const int tid = threadIdx.x;
    for (int e = tid; e < 384; e += 256) {
        rb[e] = sboxes[(size_t)(b * PRE + i0) * 6 + e];
        cb[e] = sboxes[(size_t)(b * PRE + j0) * 6 + e];
    }
    __syncthreads();
    const int wave = tid >> 6, lane = tid & 63;
    const float bx1 = cb[lane * 6 + 0], by1 = cb[lane * 6 + 1], bz1 = cb[lane * 6 + 2];
    const float bx2 = cb[lane * 6 + 3], by2 = cb[lane * 6 + 4], bz2 = cb[lane * 6 + 5];
    const float vb = (bx2 - bx1 + 1.f) * (by2 - by1 + 1.f) * (bz2 - bz1 + 1.f);
    const int j = j0 + lane;
    for (int rr = 0; rr < 16; ++rr) {
        const int il = wave * 16 + rr;
        const int i = i0 + il;
        float ax1 = rb[il * 6 + 0], ay1 = rb[il * 6 + 1], az1 = rb[il * 6 + 2];
        float ax2 = rb[il * 6 + 3], ay2 = rb[il * 6 + 4], az2 = rb[il * 6 + 5];
        float va = (ax2 - ax1 + 1.f) * (ay2 - ay1 + 1.f) * (az2 - az1 + 1.f);
        float ix = fmaxf(fminf(ax2, bx2) - fmaxf(ax1, bx1) + 1.f, 0.f);
        float iy = fmaxf(fminf(ay2, by2) - fmaxf(ay1, by1) + 1.f, 0.f);
        float iz = fmaxf(fminf(az2, bz2) - fmaxf(az1, bz1) + 1.f, 0.f);
        float inter = ix * iy * iz;
        float iou = inter / (va + vb - inter);
        bool bit = (j > i) && (iou > NMS_TH);
        unsigned long long word = __ballot(bit);
        if (lane == 0) mask[(size_t)(b * PRE + i) * 32 + (j0 >> 6)] = word;
    }
}

// single-wave greedy NMS scan + ROI output; 8-deep mask-row prefetch.
__global__ __launch_bounds__(64) void k_nms(const unsigned long long* __restrict__ mask,
                                            const float* __restrict__ sboxes,
                                            float* __restrict__ out) {
    const int b = blockIdx.x, lane = threadIdx.x;
    __shared__ int sel[POST];
    unsigned long long keep = ~0ull;          // lane l<32 owns bits [64l,64l+64)
    const int lw = lane & 31;
    const unsigned long long* mrow = mask + (size_t)b * PRE * 32 + lw;
    unsigned long long b0 = mrow[0 * 32], b1 = mrow[1 * 32], b2 = mrow[2 * 32], b3 = mrow[3 * 32];
    unsigned long long b4 = mrow[4 * 32], b5 = mrow[5 * 32], b6 = mrow[6 * 32], b7 = mrow[7 * 32];
    int kcount = 0;

#define NMS_STEP(J, BUF)                                                        \
    {                                                                           \
        int i = i0 + (J);                                                       \
        unsigned long long cur = (lw >= (i >> 6)) ? BUF : 0ull;                 \
        int nr = i0 + 8 + (J);                                                  \
        BUF = (nr < PRE) ? mrow[(size_t)nr * 32] : 0ull;                        \
        unsigned long long kw = __shfl(keep, i >> 6);                           \
        if ((kw >> (i & 63)) & 1ull) {                                          \
            if (lane < 32) keep &= ~cur;                                        \
            if (lane == 0 && kcount < POST) sel[kcount] = i;                    \
            ++kcount;                                                           \
            if (kcount >= POST) goto nms_done;                                  \
        }                                                                       \
    }

    for (int i0 = 0; i0 < PRE; i0 += 8) {
        NMS_STEP(0, b0) NMS_STEP(1, b1) NMS_STEP(2, b2) NMS_STEP(3, b3)
        NMS_STEP(4, b4) NMS_STEP(5, b5) NMS_STEP(6, b6) NMS_STEP(7, b7)
    }
nms_done:
    __syncthreads();
    const int kc = kcount;
    for (int r = lane; r < POST; r += 64) {
        float* op = &out[(size_t)(b * POST + r) * 7];
        op[0] = (float)b;
        if (r < kc) {
            const float* sb = &sboxes[(size_t)(b * PRE + sel[r]) * 6];
            #pragma unroll
            for (int c = 0; c < 6; ++c) op[1 + c] = sb[c];
        } else {
            #pragma unroll
            for (int c = 0; c < 6; ++c) op[1 + c] = 0.f;
        }
    }
#undef NMS_STEP
}

extern "C" void kernel_launch(void* const* d_in, const int* in_sizes, int n_in,
                              void* d_out, int out_size, void* d_ws, size_t ws_size,
                              hipStream_t stream) {
    const float* base_feat = (const float*)d_in[0];
    const float* im_info   = (const float*)d_in[1];
    const float* W_conv    = (const float*)d_in[4];
    const float* b_conv    = (const float*)d_in[5];
    const float* W_cls     = (const float*)d_in[6];
    const float* b_cls     = (const float*)d_in[7];
    const float* W_bbox    = (const float*)d_in[8];
    const float* b_bbox    = (const float*)d_in[9];

    char* ws = (char*)d_ws;
    u16* Wg        = (u16*)(ws + OFF_WT);
    float* Wht     = (float*)(ws + OFF_WHT);
    float* x       = (float*)(ws + OFF_X);
    float* scores  = (float*)(ws + OFF_SC);
    float* boxes   = (float*)(ws + OFF_BX);
    float* sboxes  = (float*)(ws + OFF_SB);
    unsigned long long* mask = (unsigned long long*)(ws + OFF_MK);
    unsigned int* hist = (unsigned int*)(ws + OFF_HIST);
    unsigned long long* cand = (unsigned long long*)(ws + OFF_CAND);
    u16* xh        = (u16*)(ws + OFF_XH);
    u16* xl        = (u16*)(ws + OFF_XL);

    const int NTRANS = NT_WT + NT_WHT;
    k_wtrans<<<(NTRANS + 255) / 256, 256, 0, stream>>>(W_conv, Wg, W_cls, W_bbox, Wht);
    if (ws_size >= WS_NEED_FAST) {
        k_split<<<512, 256, 0, stream>>>(base_feat, xh, xl);
        k_conv_f<<<dim3(64, 4, 2), 256, 0, stream>>>(xh, xl, Wg, b_conv, x);
    } else {
        k_conv<<<dim3(64, 4, 2), 256, 0, stream>>>(base_feat, Wg, b_conv, x);
    }
    // Wg region dead now; zero hist (aliases Wg) AFTER conv, before k_heads.
    hipMemsetAsync(hist, 0, BATCH * 65536 * sizeof(unsigned int), stream);
    k_heads<<<dim3(64, 2), 256, 0, stream>>>(x, Wht, b_cls, b_bbox, im_info, scores, boxes, hist);
    k_cutcompact<<<BATCH, 1024, 0, stream>>>(scores, hist, cand);
    k_sort2<<<BATCH, 1024, 0, stream>>>(cand, boxes, sboxes);
    k_mask<<<dim3(32, 32, 2), 256, 0, stream>>>(sboxes, mask);
    k_nms<<<BATCH, 64, 0, stream>>>(mask, sboxes, (float*)d_out);
}

// Round 7
// 642.201 us; speedup vs baseline: 1.0387x; 1.0387x over previous
//
#include <hip/hip_runtime.h>
#include <stdint.h>

// Problem constants
#define BATCH 2
#define CIN 128
#define COUT 512
#define DD 8
#define PSPAT 8192          // D*H*W
#define NA 9                // anchors per position
#define NANCH 73728         // PSPAT*NA
#define PRE 2048
#define POST 300
#define CAP 4096            // candidate buffer (top-2048 + cutoff-bin ties)
#define NMS_TH 0.7f

typedef unsigned short u16;
typedef _Float16 f16x8 __attribute__((ext_vector_type(8)));
typedef float f32x16 __attribute__((ext_vector_type(16)));
typedef unsigned int uint32x4 __attribute__((ext_vector_type(4)));

// ws layout (byte offsets). Base footprint = proven 46,104,576 B.
// R19: T4 counted-vmcnt schedule in k_conv_f. R16/R18 showed MfmaUtil pinned
// at ~21% independent of VALU load: the per-stage __syncthreads (s_waitcnt
// vmcnt(0) + s_barrier) drained the 24 just-issued next-stage loads every
// stage (~11k of 14.2k cyc/stage = stall). Now: raw s_barrier + counted
// s_waitcnt vmcnt(24/16) — loads stay in flight across barriers (m218:
// counted-vs-drain = +38-73% on GEMM). Numerics bit-identical.
// ws >= 54,493,184 B confirmed by R18 (fast path ran & passed).
constexpr size_t OFF_WT   = 0;          // 108*2 blocks * 32KB = 7,077,888 B (f16 hi/lo image)
constexpr size_t OFF_WHT  = 7077888;    // 512*80 f32       = 163,840 B
constexpr size_t OFF_X    = 7241728;    // 2*512*8192 f32   = 33,554,432 B
constexpr size_t OFF_SC   = 40796160;   // 2*73728 f32      = 589,824 B
constexpr size_t OFF_BX   = 41385984;   // 2*73728*6 f32    = 3,538,944 B
constexpr size_t OFF_SB   = 44957696;   // 2*2048*6 f32     = 98,304 B
constexpr size_t OFF_MK   = 45056000;   // 2*2048*32 u64    = 1,048,576 B  (end 46,104,576)
// selection scratch inside [0, OFF_WT+7MB), used only after k_conv:
constexpr size_t OFF_HIST = 16;              // 2*65536 u32 = 524,288 B
constexpr size_t OFF_CAND = 524304;          // 2*4096 u64  = 65,536 B
// fast-path act planes (only if ws_size >= WS_NEED_FAST):
constexpr size_t OFF_XH   = 46104576;   // [b][d][h][w][ci] f16 = 4,194,304 B
constexpr size_t OFF_XL   = 50298880;   // 4,194,304 B
constexpr size_t WS_NEED_FAST = 54493184;

// ---------------- fused weight transforms (one launch) ----------------
// Wg: per (nt,tap,cihalf): 32 KB block = 128 rows (local cout) x 256 B.
// Row n holds 64 hi f16 then 64 lo f16, as 16 columns of 16 B, stored
// column = logical ^ (n&15) (4-bit XOR swizzle; bijective). EXACT LDS image
// k_conv wants -> global_load_lds copies linearly (pre-swizzled-source,
// m173); ds_read_b128 frag reads measured 0 bank conflicts (R15/R16/R18).
// f16 split with x1024 scale: wh+wl = 1024*w, residual floor ~2^-22 rel.
#define NT_WT   (27 * 128 * 512)
#define NT_WHT  (512 * 80)
__global__ void k_wtrans(const float* __restrict__ Wc, u16* __restrict__ Wg,
                         const float* __restrict__ Wcls, const float* __restrict__ Wbb,
                         float* __restrict__ Wht) {
    int e = blockIdx.x * blockDim.x + threadIdx.x;
    if (e < NT_WT) {
        const int k    = e & 63;
        const int n    = (e >> 6) & 127;
        const int half = (e >> 13) & 1;
        const int rest = e >> 14;            // nt*27 + tap, [0,108)
        const int co = (rest / 27) * 128 + n;
        const int ci = half * 64 + k;
        const int tp = rest % 27;
        const float v = Wc[(co * 128 + ci) * 27 + tp] * 1024.f;
        const _Float16 h = (_Float16)v;
        const _Float16 l = (_Float16)(v - (float)h);
        char* rb = (char*)Wg + (((size_t)(rest * 2 + half)) << 15) + n * 256;
        const int hcol = (k >> 3) ^ (n & 15);
        const int lcol = ((k >> 3) | 8) ^ (n & 15);
        const int kb = (k & 7) << 1;
        *(u16*)(rb + (hcol << 4) + kb) = __builtin_bit_cast(unsigned short, h);
        *(u16*)(rb + (lcol << 4) + kb) = __builtin_bit_cast(unsigned short, l);
        return;
    }
    e -= NT_WT;
    if (e >= NT_WHT) return;
    int q = e % 80;
    int c = e / 80;
    int og = q / 10, k = q % 10;
    int o = og * 9 + k;
    float v = 0.f;
    if (k < 9) v = (o < 18) ? Wcls[o * 512 + c] : Wbb[(o - 18) * 512 + c];
    Wht[e] = v;
}

// ---------------- input transpose + f16 hi/lo split (fast path only) ----------------
// base_feat [b][128ci][8][32][32] f32 -> xh/xl [b][8][32][32][128ci] f16.
// Values: h = f16(1024*a), l = f16(1024*a - h) — BIT-IDENTICAL to the
// in-kernel split of R14/R15/R16 (same formula, same rounding).
__global__ __launch_bounds__(256) void k_split(const float* __restrict__ in,
                                               u16* __restrict__ xh, u16* __restrict__ xl) {
    __shared__ float t[128][33];
    const int blk = blockIdx.x;                  // b*256 + d*32 + h
    const int b = blk >> 8, d = (blk >> 5) & 7, h = blk & 31;
    const int tid = threadIdx.x;
    const float* src = in + ((size_t)b << 20) + d * 1024 + h * 32;
    #pragma unroll
    for (int i = 0; i < 16; ++i) {
        const int e = tid + i * 256;
        const int ci = e >> 5, w = e & 31;
        t[ci][w] = src[(size_t)ci * 8192 + w];
    }
    __syncthreads();
    const size_t ob = (size_t)((b * 8 + d) * 32 + h) * 4096;   // *32w*128ci
    #pragma unroll
    for (int i = 0; i < 16; ++i) {
        const int e = tid + i * 256;
        const int w = e >> 7, ci = e & 127;
        const float v = t[ci][w] * 1024.f;
        const _Float16 hh = (_Float16)v;
        const _Float16 ll = (_Float16)(v - (float)hh);
        xh[ob + w * 128 + ci] = __builtin_bit_cast(unsigned short, hh);
        xl[ob + w * 128 + ci] = __builtin_bit_cast(unsigned short, ll);
    }
}

// ---------------- conv3d 3x3x3 + bias + relu: MFMA implicit GEMM ----------------
// Shared pieces (both conv variants): MFMA core, W staging, epilogue.
#define MFMA(A, B, C) __builtin_amdgcn_mfma_f32_32x32x16_f16((A), (B), (C), 0, 0, 0)
#define Z16 {0.f,0.f,0.f,0.f,0.f,0.f,0.f,0.f,0.f,0.f,0.f,0.f,0.f,0.f,0.f,0.f}

// Stage S weights (32 KB) -> LDS buffer BUF via global_load_lds, linear copy.
#define WISSUE(S, BUF) { \
    const int tap_ = t0 + ((S) >> 1); \
    const char* gw_ = WgB + (((size_t)((nt * 27 + tap_) * 2 + ((S) & 1))) << 15) \
                    + (wv << 13) + ln16; \
    char* lb_ = smem + ((BUF) << 15) + (wv << 13); \
    _Pragma("unroll") \
    for (int j_ = 0; j_ < 8; ++j_) \
        __builtin_amdgcn_global_load_lds( \
            (const __attribute__((address_space(1))) void*)(gw_ + (j_ << 10)), \
            (__attribute__((address_space(3))) void*)(lb_ + (j_ << 10)), 16, 0, 0); }

#define KKSTEP(KK, BH0, BL0, BH1, BL1) { \
    const int ch_ = ((((KK) << 1) + cq) ^ rsw) << 4; \
    const int cl_ = (((((KK) << 1) + cq) | 8) ^ rsw) << 4; \
    const char* r0_ = wb_ + (rm0 << 8); \
    const char* r1_ = wb_ + (rm1 << 8); \
    const f16x8 wh0 = *(const f16x8*)(r0_ + ch_); \
    const f16x8 wl0 = *(const f16x8*)(r0_ + cl_); \
    const f16x8 wh1 = *(const f16x8*)(r1_ + ch_); \
    const f16x8 wl1 = *(const f16x8*)(r1_ + cl_); \
    acc00 = MFMA(wh0, BH0, acc00); acc00 = MFMA(wh0, BL0, acc00); acc00 = MFMA(wl0, BH0, acc00); \
    acc01 = MFMA(wh0, BH1, acc01); acc01 = MFMA(wh0, BL1, acc01); acc01 = MFMA(wl0, BH1, acc01); \
    acc10 = MFMA(wh1, BH0, acc10); acc10 = MFMA(wh1, BL0, acc10); acc10 = MFMA(wl1, BH0, acc10); \
    acc11 = MFMA(wh1, BH1, acc11); acc11 = MFMA(wh1, BL1, acc11); acc11 = MFMA(wl1, BH1, acc11); }

// acc = 2^20 * conv -> unscale exactly, + bias, relu
#define EPI(ACC, MI, NI) { \
    const int coB_ = co0 + (wm << 6) + ((MI) << 5) + hl4; \
    const int pt_  = p0 + (wn << 6) + ((NI) << 5) + l31; \
    _Pragma("unroll") \
    for (int g_ = 0; g_ < 4; ++g_) { \
        _Pragma("unroll") \
        for (int q_ = 0; q_ < 4; ++q_) { \
            const int co_ = coB_ + (g_ << 3) + q_; \
            const float v_ = ACC[g_ * 4 + q_] * 9.5367431640625e-07f + bconv[co_]; \
            x[((size_t)((b << 9) + co_) << 13) + pt_] = fmaxf(v_, 0.f); \
        } } }

// ======== FAST conv: acts pre-split, B-frags = direct 16B loads ========
// One frag pair (N,KK): two dwordx4 loads; KK*32B folds into inst offset.
// Halo: h/w clamped IN-PLANE for the address (&31), value zeroed by cndmask.
// P is a fragment-set prefix token (A or B); P##h00 etc. are named VGPR vars.
#define FLD(N, KK, BH, BL) { \
    const int h2_ = hb_ + (N); \
    const bool ok_ = okw_ && ((unsigned)h2_ < 32u); \
    const size_t ix_ = sbase_ + ((size_t)((h2_ & 31) << 5) << 7); \
    const f16x8 vh_ = *(const f16x8*)(xh + ix_ + ((KK) << 4)); \
    const f16x8 vl_ = *(const f16x8*)(xl + ix_ + ((KK) << 4)); \
    BH = ok_ ? vh_ : fz8; \
    BL = ok_ ? vl_ : fz8; }

#define ALOADF(S, P) { \
    const int tap_ = t0 + ((S) >> 1); \
    const int kd_ = tap_ / 9, kh_ = (tap_ / 3) % 3, kw_ = tap_ % 3; \
    const int id_ = d0 + kd_ - 1; \
    const int w2_ = l31 + kw_ - 1; \
    const bool okw_ = (unsigned)w2_ < 32u; \
    const int hb_ = h0 + (wn << 1) + kh_ - 1; \
    const int cio_ = (((S) & 1) << 6) + (cq << 3); \
    const size_t sbase_ = (((size_t)((b << 3) + id_)) << 17) + ((w2_ & 31) << 7) + cio_; \
    FLD(0, 0, P##h00, P##l00) FLD(0, 1, P##h01, P##l01) \
    FLD(0, 2, P##h02, P##l02) FLD(0, 3, P##h03, P##l03) \
    FLD(1, 0, P##h10, P##l10) FLD(1, 1, P##h11, P##l11) \
    FLD(1, 2, P##h12, P##l12) FLD(1, 3, P##h13, P##l13) }

#define COMPUTEF(BUF, P) { \
    const char* wb_ = smem + ((BUF) << 15); \
    KKSTEP(0, P##h00, P##l00, P##h10, P##l10) \
    KKSTEP(1, P##h01, P##l01, P##h11, P##l11) \
    KKSTEP(2, P##h02, P##l02, P##h12, P##l12) \
    KKSTEP(3, P##h03, P##l03, P##h13, P##l13) }

// Counted waits (T4): vmcnt order per stage is pinned [8 W][16 acts] by a
// sched_barrier between WISSUE and ALOADF. No other vmem ops in the loop.
#define VMCNT24 asm volatile("s_waitcnt vmcnt(24)" ::: "memory");
#define VMCNT16 asm volatile("s_waitcnt vmcnt(16)" ::: "memory");
#define VMCNT0  asm volatile("s_waitcnt vmcnt(0)"  ::: "memory");
#define SBAR    __builtin_amdgcn_s_barrier();
#define SCHED0  __builtin_amdgcn_sched_barrier(0);

__global__ __launch_bounds__(256, 2) void k_conv_f(const u16* __restrict__ xh,
                                                   const u16* __restrict__ xl,
                                                   const u16* __restrict__ Wg,
                                                   const float* __restrict__ bconv,
                                                   float* __restrict__ x) {
    __shared__ __align__(16) char smem[65536];   // W double-buffer: 2 x 32 KB
    const int tid  = threadIdx.x;
    const int bx   = blockIdx.x;        // 64 spatial tiles (128 pts each)
    const int nt   = blockIdx.y;        // 4 cout tiles of 128
    const int b    = blockIdx.z;
    const int p0   = bx << 7;
    const int d0   = bx >> 3;
    const int h0   = (bx & 7) << 2;
    const int co0  = nt << 7;

    const int lane = tid & 63;
    const int wv   = tid >> 6;          // wave id
    const int wm   = wv & 1;            // cout 64-half
    const int wn   = wv >> 1;           // pt 64-half
    const int l31  = lane & 31;         // frag row/col
    const int cq   = lane >> 5;         // frag k-octet half
    const int hl4  = cq << 2;           // C/D row group
    const int rsw  = l31 & 15;          // W-row XOR swizzle key
    const int rm0  = (wm << 6) + l31;   // weight LDS rows (256 B each)
    const int rm1  = rm0 + 32;
    const int ln16 = lane << 4;

    const int t0   = (d0 == 0) ? 9 : 0;
    const int nTap = 27 - (((d0 == 0) || (d0 == 7)) ? 9 : 0);
    const int NS   = nTap * 2;          // stages (EVEN: 54 or 36)

    const char* WgB = (const char*)Wg;
    const f16x8 fz8 = {(_Float16)0.f, (_Float16)0.f, (_Float16)0.f, (_Float16)0.f,
                       (_Float16)0.f, (_Float16)0.f, (_Float16)0.f, (_Float16)0.f};

    f16x8 Ah00, Al00, Ah01, Al01, Ah02, Al02, Ah03, Al03,
          Ah10, Al10, Ah11, Al11, Ah12, Al12, Ah13, Al13;
    f16x8 Bh00, Bl00, Bh01, Bl01, Bh02, Bl02, Bh03, Bl03,
          Bh10, Bl10, Bh11, Bl11, Bh12, Bl12, Bh13, Bl13;
    f32x16 acc00 = Z16, acc01 = Z16, acc10 = Z16, acc11 = Z16;

    // Prologue: W(0)->buf0 (8 loads), acts(0)->A (16 loads), pinned order.
    WISSUE(0, 0)
    SCHED0
    ALOADF(0, A)
    VMCNT16                             // own W(0) landed (acts(0) may fly)
    SBAR                                // all waves' W(0) in LDS

    for (int s = 0; s < NS; s += 2) {
        // ---- even stage s: buf0 + frags A; prefetch s+1 (buf1 + B) ----
        WISSUE(s + 1, 1)                // safe: buf1 last read 2 stages ago,
        SCHED0                          //       barrier'd after that read
        ALOADF(s + 1, B)
        VMCNT24                         // acts(s) done (oldest 16 of 40)
        SCHED0
        COMPUTEF(0, A)
        VMCNT16                         // W(s+1) landed (oldest 8 of 24)
        SBAR                            // all waves: W(s+1) visible; buf0 free
        // ---- odd stage s+1: buf1 + frags B; prefetch s+2 (buf0 + A) ----
        if (s + 2 < NS) {
            WISSUE(s + 2, 0)
            SCHED0
            ALOADF(s + 2, A)
            VMCNT24                     // acts(s+1) done
        } else {
            VMCNT0                      // tail: acts(s+1) done
        }
        SCHED0
        COMPUTEF(1, B)
        if (s + 2 < NS) {
            VMCNT16                     // W(s+2) landed
            SBAR                        // buf1 free for next WISSUE(s+3,1)
        }
    }

    EPI(acc00, 0, 0)
    EPI(acc01, 0, 1)
    EPI(acc10, 1, 0)
    EPI(acc11, 1, 1)
}

// ======== FALLBACK conv (exact R16): in-kernel split, pipelined ========
// Dormant (R18 confirmed ws >= WS_NEED_FAST on the harness) but kept as the
// safety net for smaller-ws environments.
#define PK2(YA, YB, UH, UL) { \
    const float sa_ = (YA) * 1024.f, sb_ = (YB) * 1024.f; \
    const _Float16 ha_ = (_Float16)sa_, hb_ = (_Float16)sb_; \
    const _Float16 la_ = (_Float16)(sa_ - (float)ha_); \
    const _Float16 lb_ = (_Float16)(sb_ - (float)hb_); \
    UH = (unsigned)__builtin_bit_cast(unsigned short, ha_) | \
         ((unsigned)__builtin_bit_cast(unsigned short, hb_) << 16); \
    UL = (unsigned)__builtin_bit_cast(unsigned short, la_) | \
         ((unsigned)__builtin_bit_cast(unsigned short, lb_) << 16); }

#define BLDI(N, KK) { \
    const int h2_ = hb_ + (N); \
    const bool ok_ = okw_ && ((unsigned)h2_ < 32u); \
    const float* ap_ = in + (((size_t)(cb0_ + ((KK) << 4))) << 13) + spo_ + (h2_ << 5); \
    y[N][KK][0] = ok_ ? ap_[0]     : 0.f; \
    y[N][KK][1] = ok_ ? ap_[8192]  : 0.f; \
    y[N][KK][2] = ok_ ? ap_[16384] : 0.f; \
    y[N][KK][3] = ok_ ? ap_[24576] : 0.f; \
    y[N][KK][4] = ok_ ? ap_[32768] : 0.f; \
    y[N][KK][5] = ok_ ? ap_[40960] : 0.f; \
    y[N][KK][6] = ok_ ? ap_[49152] : 0.f; \
    y[N][KK][7] = ok_ ? ap_[57344] : 0.f; }

#define ALOADISS(S) { \
    const int tap_ = t0 + ((S) >> 1); \
    const int kd_ = tap_ / 9, kh_ = (tap_ / 3) % 3, kw_ = tap_ % 3; \
    const int id_ = d0 + kd_ - 1; \
    const int w2_ = l31 + kw_ - 1; \
    const bool okw_ = (unsigned)w2_ < 32u; \
    const int hb_ = h0 + (wn << 1) + kh_ - 1; \
    const int cb0_ = b * CIN + (((S) & 1) << 6) + (cq << 3); \
    const long long spo_ = ((long long)id_ << 10) + w2_; \
    BLDI(0, 0) BLDI(0, 1) BLDI(0, 2) BLDI(0, 3) \
    BLDI(1, 0) BLDI(1, 1) BLDI(1, 2) BLDI(1, 3) }

#define CVTFRAG(N, KK, BH, BL) { \
    unsigned uh0_, uh1_, uh2_, uh3_, ul0_, ul1_, ul2_, ul3_; \
    PK2(y[N][KK][0], y[N][KK][1], uh0_, ul0_) \
    PK2(y[N][KK][2], y[N][KK][3], uh1_, ul1_) \
    PK2(y[N][KK][4], y[N][KK][5], uh2_, ul2_) \
    PK2(y[N][KK][6], y[N][KK][7], uh3_, ul3_) \
    { uint32x4 th_ = {uh0_, uh1_, uh2_, uh3_}; BH = __builtin_bit_cast(f16x8, th_); } \
    { uint32x4 tl_ = {ul0_, ul1_, ul2_, ul3_}; BL = __builtin_bit_cast(f16x8, tl_); } }

#define CVTALL() { \
    CVTFRAG(0, 0, bh00, bl00) CVTFRAG(0, 1, bh01, bl01) \
    CVTFRAG(0, 2, bh02, bl02) CVTFRAG(0, 3, bh03, bl03) \
    CVTFRAG(1, 0, bh10, bl10) CVTFRAG(1, 1, bh11, bl11) \
    CVTFRAG(1, 2, bh12, bl12) CVTFRAG(1, 3, bh13, bl13) }

#define COMPUTE(BUF) { \
    const char* wb_ = smem + ((BUF) << 15); \
    KKSTEP(0, bh00, bl00, bh10, bl10) \
    KKSTEP(1, bh01, bl01, bh11, bl11) \
    KKSTEP(2, bh02, bl02, bh12, bl12) \
    KKSTEP(3, bh03, bl03, bh13, bl13) }

__global__ __launch_bounds__(256, 2) void k_conv(const float* __restrict__ in,
                                                 const u16* __restrict__ Wg,
                                                 const float* __restrict__ bconv,
                                                 float* __restrict__ x) {
    __shared__ __align__(16) char smem[65536];   // W double-buffer: 2 x 32 KB
    const int tid  = threadIdx.x;
    const int bx   = blockIdx.x;
    const int nt   = blockIdx.y;
    const int b    = blockIdx.z;
    const int p0   = bx << 7;
    const int d0   = bx >> 3;
    const int h0   = (bx & 7) << 2;
    const int co0  = nt << 7;

    const int lane = tid & 63;
    const int wv   = tid >> 6;
    const int wm   = wv & 1;
    const int wn   = wv >> 1;
    const int l31  = lane & 31;
    const int cq   = lane >> 5;
    const int hl4  = cq << 2;
    const int rsw  = l31 & 15;
    const int rm0  = (wm << 6) + l31;
    const int rm1  = rm0 + 32;
    const int ln16 = lane << 4;

    const int t0   = (d0 == 0) ? 9 : 0;
    const int nTap = 27 - (((d0 == 0) || (d0 == 7)) ? 9 : 0);
    const int NS   = nTap * 2;

    const char* WgB = (const char*)Wg;

    float y[2][4][8];
    f16x8 bh00, bh01, bh02, bh03, bh10, bh11, bh12, bh13;
    f16x8 bl00, bl01, bl02, bl03, bl10, bl11, bl12, bl13;
    f32x16 acc00 = Z16, acc01 = Z16, acc10 = Z16, acc11 = Z16;

    WISSUE(0, 0)
    ALOADISS(0)
    __syncthreads();

    for (int s = 0; s < NS; ++s) {
        if (s + 1 < NS) { WISSUE(s + 1, (s + 1) & 1) }
        CVTALL()
        __builtin_amdgcn_sched_barrier(0);
        if (s + 1 < NS) { ALOADISS(s + 1) }
        __builtin_amdgcn_sched_barrier(0);
        COMPUTE(s & 1)
        __syncthreads();
    }

    EPI(acc00, 0, 0)
    EPI(acc01, 0, 1)
    EPI(acc10, 1, 0)
    EPI(acc11, 1, 1)
}

// ---------------- heads GEMM + score/box epilogue + fused score histogram ----------------
// R12 form (measured best): unchanged.
__global__ __launch_bounds__(256) void k_heads(const float* __restrict__ x,
                                               const float* __restrict__ Wht,
                                               const float* __restrict__ bcls,
                                               const float* __restrict__ bbb,
                                               const float* __restrict__ iminfo,
                                               float* __restrict__ scores,
                                               float* __restrict__ boxes,
                                               unsigned int* __restrict__ hist) {
    __shared__ __align__(16) float smx[4096];    // x chunk [ch32][pt128]  16 KB
    __shared__ __align__(16) float Whs[2560];    // weight chunk [kk32][80] 10 KB
    __shared__ __align__(16) float ex[10240];    // exchange [pt128][80]    40 KB
    const int tid = threadIdx.x;
    const int p0  = blockIdx.x * 128;
    const int b   = blockIdx.y;
    const int pl  = tid & 31;     // 32 point-lanes, 4 consecutive points each
    const int og  = tid >> 5;     // 8 output groups of 9

    float acc[4][9] = {};

    for (int cc = 0; cc < 512; cc += 32) {
        __syncthreads();
        #pragma unroll
        for (int i = 0; i < 4; ++i) {
            int e4 = tid + i * 256;          // 1024 float4s
            int ch = e4 >> 5;
            int pt4 = (e4 & 31) * 4;
            *(float4*)&smx[ch * 128 + pt4] =
                *(const float4*)&x[((size_t)(b * COUT + cc + ch) << 13) + p0 + pt4];
        }
        #pragma unroll
        for (int i = 0; i < 10; ++i) {
            int e = tid + i * 256;
            Whs[e] = Wht[cc * 80 + e];
        }
        __syncthreads();
        for (int kk = 0; kk < 32; ++kk) {
            float4 a4 = *(const float4*)&smx[kk * 128 + pl * 4];
            const float* wp = &Whs[kk * 80 + og * 10];
            float2 w0 = *(const float2*)(wp);
            float2 w1 = *(const float2*)(wp + 2);
            float2 w2 = *(const float2*)(wp + 4);
            float2 w3 = *(const float2*)(wp + 6);
            float  w8 = wp[8];
            float wv[9] = {w0.x, w0.y, w1.x, w1.y, w2.x, w2.y, w3.x, w3.y, w8};
            #pragma unroll
            for (int k = 0; k < 9; ++k) {
                float wk = wv[k];
                acc[0][k] += a4.x * wk;
                acc[1][k] += a4.y * wk;
                acc[2][k] += a4.z * wk;
                acc[3][k] += a4.w * wk;
            }
        }
    }

    __syncthreads();
    #pragma unroll
    for (int pi = 0; pi < 4; ++pi)
        #pragma unroll
        for (int k = 0; k < 9; ++k)
            ex[(pl * 4 + pi) * 80 + og * 10 + k] = acc[pi][k];
    __syncthreads();

    if (tid < 128) {
        const int p = p0 + tid;
        float v[72];
        #pragma unroll
        for (int og2 = 0; og2 < 8; ++og2)
            #pragma unroll
            for (int k = 0; k < 9; ++k)
                v[og2 * 9 + k] = ex[tid * 80 + og2 * 10 + k];

        const float im0 = iminfo[b * 3 + 0], im1 = iminfo[b * 3 + 1], im2 = iminfo[b * 3 + 2];
        const float hix = im2 - 1.f, hiy = im1 - 1.f, hiz = im0 - 1.f;
        const int d = p >> 10, h = (p >> 5) & 31, w = p & 31;
        const float sx = w * 8.f, sy = h * 8.f, sz = d * 8.f;

        #pragma unroll 1
        for (int a = 0; a < 9; ++a) {
            float c0 = v[a] + bcls[a];
            float c1 = v[9 + a] + bcls[9 + a];
            float m  = fmaxf(c0, c1);
            float e0 = expf(c0 - m), e1 = expf(c1 - m);
            float sc = e1 / (e0 + e1);
            scores[b * NANCH + p * 9 + a] = sc;
            atomicAdd(&hist[b * 65536 + (__float_as_uint(sc) >> 16)], 1u);

            float aw = (float)(32 << (a % 3));                 // x,y size = 8*SCALES
            float ad = aw * 0.5f * (float)(1 << (a / 3));      // z size = aw*RATIOS
            float ax1 = sx + 3.5f - 0.5f * (aw - 1.f);
            float ax2 = sx + 3.5f + 0.5f * (aw - 1.f);
            float ay1 = sy + 3.5f - 0.5f * (aw - 1.f);
            float ay2 = sy + 3.5f + 0.5f * (aw - 1.f);
            float az1 = sz + 3.5f - 0.5f * (ad - 1.f);
            float az2 = sz + 3.5f + 0.5f * (ad - 1.f);
            float ww_ = ax2 - ax1 + 1.f, hh_ = ay2 - ay1 + 1.f, dd_ = az2 - az1 + 1.f;
            float cx = ax1 + 0.5f * ww_, cy = ay1 + 0.5f * hh_, cz = az1 + 0.5f * dd_;

            const float* dv = &v[18 + a * 6];
            float dx = dv[0] + bbb[a * 6 + 0];
            float dy = dv[1] + bbb[a * 6 + 1];
            float dz = dv[2] + bbb[a * 6 + 2];
            float dw = dv[3] + bbb[a * 6 + 3];
            float dh = dv[4] + bbb[a * 6 + 4];
            float dd2 = dv[5] + bbb[a * 6 + 5];
            float pcx = dx * ww_ + cx, pcy = dy * hh_ + cy, pcz = dz * dd_ + cz;
            float pw = expf(dw) * ww_, ph = expf(dh) * hh_, pd = expf(dd2) * dd_;
            float x1 = fminf(fmaxf(pcx - 0.5f * pw, 0.f), hix);
            float y1 = fminf(fmaxf(pcy - 0.5f * ph, 0.f), hiy);
            float z1 = fminf(fmaxf(pcz - 0.5f * pd, 0.f), hiz);
            float x2 = fminf(fmaxf(pcx + 0.5f * pw, 0.f), hix);
            float y2 = fminf(fmaxf(pcy + 0.5f * ph, 0.f), hiy);
            float z2 = fminf(fmaxf(pcz + 0.5f * pd, 0.f), hiz);
            float* bp = &boxes[(size_t)(b * NANCH + p * 9 + a) * 6];
            bp[0] = x1; bp[1] = y1; bp[2] = z1; bp[3] = x2; bp[4] = y2; bp[5] = z2;
        }
    }
}

// ---------------- fused cutoff + compact (one block per batch) ----------------
__global__ __launch_bounds__(1024) void k_cutcompact(const float* __restrict__ scores,
                                                     const unsigned int* __restrict__ hist,
                                                     unsigned long long* __restrict__ cand) {
    __shared__ unsigned int cs[1024], scan[1024];
    __shared__ unsigned int sh_cut, sh_pos;
    const int b = blockIdx.x, tid = threadIdx.x;
    const unsigned int* h = hist + b * 65536;
    unsigned int s = 0;
    for (int i = 0; i < 64; ++i) s += h[tid * 64 + i];
    cs[tid] = s; scan[tid] = s;
    if (tid == 0) sh_pos = 0;
    __syncthreads();
    for (int d = 1; d < 1024; d <<= 1) {           // scan[c] -> sum_{c'>=c} cs[c']
        unsigned int v = scan[tid];
        unsigned int add = (tid + d < 1024) ? scan[tid + d] : 0u;
        __syncthreads();
        scan[tid] = v + add;
        __syncthreads();
    }
    unsigned int above = (tid + 1 < 1024) ? scan[tid + 1] : 0u;   // strictly above this chunk
    if (above < PRE && above + cs[tid] >= PRE) {   // exactly one thread
        unsigned int cum = above;
        for (int x = tid * 64 + 63; x >= tid * 64; --x) {
            cum += h[x];
            if (cum >= PRE) { sh_cut = (unsigned int)x; break; }
        }
    }
    __syncthreads();
    const unsigned int cut = sh_cut;
    const float* sc = scores + b * NANCH;
    for (int i = tid; i < NANCH; i += 1024) {
        unsigned int u = __float_as_uint(sc[i]);
        if ((u >> 16) >= cut) {
            unsigned int pos = atomicAdd(&sh_pos, 1u);
            if (pos < CAP) cand[b * CAP + pos] = ((unsigned long long)(~u) << 32) | (unsigned)i;
        }
    }
    __syncthreads();
    const unsigned int cnt = (sh_pos < CAP) ? sh_pos : CAP;
    for (int i = (int)cnt + tid; i < CAP; i += 1024)
        cand[b * CAP + i] = ~0ull;
}

// bitonic sort CAP keys asc (key = ~score_bits || idx => score desc, idx asc);
// first 2048 are the sorted top-2048; gather their boxes.
__global__ __launch_bounds__(1024) void k_sort2(const unsigned long long* __restrict__ cand,
                                                const float* __restrict__ boxes,
                                                float* __restrict__ sboxes) {
    __shared__ unsigned long long sk[CAP];
    const int b = blockIdx.x, tid = threadIdx.x;
    for (int i = tid; i < CAP; i += 1024) sk[i] = cand[b * CAP + i];
    __syncthreads();
    for (int k = 2; k <= CAP; k <<= 1) {
        for (int j = k >> 1; j > 0; j >>= 1) {
            #pragma unroll 1
            for (int i = tid; i < CAP; i += 1024) {
                int ixj = i ^ j;
                if (ixj > i) {
                    unsigned long long va = sk[i], vb = sk[ixj];
                    bool up = ((i & k) == 0);
                    if ((va > vb) == up) { sk[i] = vb; sk[ixj] = va; }
                }
            }
            __syncthreads();
        }
    }
    for (int r = tid; r < PRE; r += 1024) {
        unsigned int n = (unsigned int)(sk[r] & 0xFFFFFFFFull);
        const float* src = &boxes[(size_t)(b * NANCH + (int)n) * 6];
        float* dst = &sboxes[(size_t)(b * PRE + r) * 6];
        #pragma unroll
        for (int c = 0; c < 6; ++c) dst[c] = src[c];
    }
}

// suppression bitmask (upper triangle only): mask[b][i][w] bit j <=> j>i && IoU>0.7
__global__ __launch_bounds__(256) void k_mask(const float* __restrict__ sboxes,
                                              unsigned long long* __restrict__ mask) {
    if (blockIdx.y < blockIdx.x) return;   // j0 < i0: never read (k_nms gates by word)
    __shared__ float rb[64 * 6], cb[64 * 6];
    const int i0 = blockIdx.x * 64, j0 = blockIdx.y * 64, b = blockIdx.z;
    const int tid = threadIdx.x;
    for (int e = tid; e < 384; e += 256) {
        rb[e] = sboxes[(size_t)(b * PRE + i0) * 6 + e];
        cb[e] = sboxes[(size_t)(b * PRE + j0) * 6 + e];
    }
    __syncthreads();
    const int wave = tid >> 6, lane = tid & 63;
    const float bx1 = cb[lane * 6 + 0], by1 = cb[lane * 6 + 1], bz1 = cb[lane * 6 + 2];
    const float bx2 = cb[lane * 6 + 3], by2 = cb[lane * 6 + 4], bz2 = cb[lane * 6 + 5];
    const float vb = (bx2 - bx1 + 1.f) * (by2 - by1 + 1.f) * (bz2 - bz1 + 1.f);
    const int j = j0 + lane;
    for (int rr = 0; rr < 16; ++rr) {
        const int il = wave * 16 + rr;
        const int i = i0 + il;
        float ax1 = rb[il * 6 + 0], ay1 = rb[il * 6 + 1], az1 = rb[il * 6 + 2];
        float ax2 = rb[il * 6 + 3], ay2 = rb[il * 6 + 4], az2 = rb[il * 6 + 5];
        float va = (ax2 - ax1 + 1.f) * (ay2 - ay1 + 1.f) * (az2 - az1 + 1.f);
        float ix = fmaxf(fminf(ax2, bx2) - fmaxf(ax1, bx1) + 1.f, 0.f);
        float iy = fmaxf(fminf(ay2, by2) - fmaxf(ay1, by1) + 1.f, 0.f);
        float iz = fmaxf(fminf(az2, bz2) - fmaxf(az1, bz1) + 1.f, 0.f);
        float inter = ix * iy * iz;
        float iou = inter / (va + vb - inter);
        bool bit = (j > i) && (iou > NMS_TH);
        unsigned long long word = __ballot(bit);
        if (lane == 0) mask[(size_t)(b * PRE + i) * 32 + (j0 >> 6)] = word;
    }
}

// single-wave greedy NMS scan + ROI output; 8-deep mask-row prefetch.
__global__ __launch_bounds__(64) void k_nms(const unsigned long long* __restrict__ mask,
                                            const float* __restrict__ sboxes,
                                            float* __restrict__ out) {
    const int b = blockIdx.x, lane = threadIdx.x;
    __shared__ int sel[POST];
    unsigned long long keep = ~0ull;          // lane l<32 owns bits [64l,64l+64)
    const int lw = lane & 31;
    const unsigned long long* mrow = mask + (size_t)b * PRE * 32 + lw;
    unsigned long long b0 = mrow[0 * 32], b1 = mrow[1 * 32], b2 = mrow[2 * 32], b3 = mrow[3 * 32];
    unsigned long long b4 = mrow[4 * 32], b5 = mrow[5 * 32], b6 = mrow[6 * 32], b7 = mrow[7 * 32];
    int kcount = 0;

#define NMS_STEP(J, BUF)                                                        \
    {                                                                           \
        int i = i0 + (J);                                                       \
        unsigned long long cur = (lw >= (i >> 6)) ? BUF : 0ull;                 \
        int nr = i0 + 8 + (J);                                                  \
        BUF = (nr < PRE) ? mrow[(size_t)nr * 32] : 0ull;                        \
        unsigned long long kw = __shfl(keep, i >> 6);                           \
        if ((kw >> (i & 63)) & 1ull) {                                          \
            if (lane < 32) keep &= ~cur;                                        \
            if (lane == 0 && kcount < POST) sel[kcount] = i;                    \
            ++kcount;                                                           \
            if (kcount >= POST) goto nms_done;                                  \
        }                                                                       \
    }

    for (int i0 = 0; i0 < PRE; i0 += 8) {
        NMS_STEP(0, b0) NMS_STEP(1, b1) NMS_STEP(2, b2) NMS_STEP(3, b3)
        NMS_STEP(4, b4) NMS_STEP(5, b5) NMS_STEP(6, b6) NMS_STEP(7, b7)
    }
nms_done:
    __syncthreads();
    const int kc = kcount;
    for (int r = lane; r < POST; r += 64) {
        float* op = &out[(size_t)(b * POST + r) * 7];
        op[0] = (float)b;
        if (r < kc) {
            const float* sb = &sboxes[(size_t)(b * PRE + sel[r]) * 6];
            #pragma unroll
            for (int c = 0; c < 6; ++c) op[1 + c] = sb[c];
        } else {
            #pragma unroll
            for (int c = 0; c < 6; ++c) op[1 + c] = 0.f;
        }
    }
#undef NMS_STEP
}

extern "C" void kernel_launch(void* const* d_in, const int* in_sizes, int n_in,
                              void* d_out, int out_size, void* d_ws, size_t ws_size,
                              hipStream_t stream) {
    const float* base_feat = (const float*)d_in[0];
    const float* im_info   = (const float*)d_in[1];
    const float* W_conv    = (const float*)d_in[4];
    const float* b_conv    = (const float*)d_in[5];
    const float* W_cls     = (const float*)d_in[6];
    const float* b_cls     = (const float*)d_in[7];
    const float* W_bbox    = (const float*)d_in[8];
    const float* b_bbox    = (const float*)d_in[9];

    char* ws = (char*)d_ws;
    u16* Wg        = (u16*)(ws + OFF_WT);
    float* Wht     = (float*)(ws + OFF_WHT);
    float* x       = (float*)(ws + OFF_X);
    float* scores  = (float*)(ws + OFF_SC);
    float* boxes   = (float*)(ws + OFF_BX);
    float* sboxes  = (float*)(ws + OFF_SB);
    unsigned long long* mask = (unsigned long long*)(ws + OFF_MK);
    unsigned int* hist = (unsigned int*)(ws + OFF_HIST);
    unsigned long long* cand = (unsigned long long*)(ws + OFF_CAND);
    u16* xh        = (u16*)(ws + OFF_XH);
    u16* xl        = (u16*)(ws + OFF_XL);

    const int NTRANS = NT_WT + NT_WHT;
    k_wtrans<<<(NTRANS + 255) / 256, 256, 0, stream>>>(W_conv, Wg, W_cls, W_bbox, Wht);
    if (ws_size >= WS_NEED_FAST) {
        k_split<<<512, 256, 0, stream>>>(base_feat, xh, xl);
        k_conv_f<<<dim3(64, 4, 2), 256, 0, stream>>>(xh, xl, Wg, b_conv, x);
    } else {
        k_conv<<<dim3(64, 4, 2), 256, 0, stream>>>(base_feat, Wg, b_conv, x);
    }
    // Wg region dead now; zero hist (aliases Wg) AFTER conv, before k_heads.
    hipMemsetAsync(hist, 0, BATCH * 65536 * sizeof(unsigned int), stream);
    k_heads<<<dim3(64, 2), 256, 0, stream>>>(x, Wht, b_cls, b_bbox, im_info, scores, boxes, hist);
    k_cutcompact<<<BATCH, 1024, 0, stream>>>(scores, hist, cand);
    k_sort2<<<BATCH, 1024, 0, stream>>>(cand, boxes, sboxes);
    k_mask<<<dim3(32, 32, 2), 256, 0, stream>>>(sboxes, mask);
    k_nms<<<BATCH, 64, 0, stream>>>(mask, sboxes, (float*)d_out);
}

// Round 8
// 557.110 us; speedup vs baseline: 1.1974x; 1.1527x over previous
//
#include <hip/hip_runtime.h>
#include <stdint.h>

// Problem constants
#define BATCH 2
#define CIN 128
#define COUT 512
#define DD 8
#define PSPAT 8192          // D*H*W
#define NA 9                // anchors per position
#define NANCH 73728         // PSPAT*NA
#define PRE 2048
#define POST 300
#define CAP 4096            // candidate buffer (top-2048 + cutoff-bin ties)
#define NMS_TH 0.7f

typedef unsigned short u16;
typedef _Float16 f16x8 __attribute__((ext_vector_type(8)));
typedef float f32x16 __attribute__((ext_vector_type(16)));
typedef unsigned int uint32x4 __attribute__((ext_vector_type(4)));

// ws layout (byte offsets). Base footprint = proven 46,104,576 B.
// R20: act planes re-tiled to octet-interleaved [b][d][h][oct16][w32][8ci]
// so k_conv_f's B-frag loads are FULLY COALESCED (512B contiguous per 32
// lanes, 8 fully-used lines/instr vs 32 quarter-used before). R19 diagnosis:
// MfmaUtil pinned ~23% with VALU/LDS/HBM all idle — the [w][128ci] layout
// made each frag load a 32-line gather (512 TA requests/wave/stage), the
// address-unit was the critical pipe. Also: KKSTEP MFMAs re-ordered into 3
// rounds of 4 independent accs (per-acc product order preserved ->
// bit-identical numerics).
constexpr size_t OFF_WT   = 0;          // 108*2 blocks * 32KB = 7,077,888 B (f16 hi/lo image)
constexpr size_t OFF_WHT  = 7077888;    // 512*80 f32       = 163,840 B
constexpr size_t OFF_X    = 7241728;    // 2*512*8192 f32   = 33,554,432 B
constexpr size_t OFF_SC   = 40796160;   // 2*73728 f32      = 589,824 B
constexpr size_t OFF_BX   = 41385984;   // 2*73728*6 f32    = 3,538,944 B
constexpr size_t OFF_SB   = 44957696;   // 2*2048*6 f32     = 98,304 B
constexpr size_t OFF_MK   = 45056000;   // 2*2048*32 u64    = 1,048,576 B  (end 46,104,576)
// selection scratch inside [0, OFF_WT+7MB), used only after k_conv:
constexpr size_t OFF_HIST = 16;              // 2*65536 u32 = 524,288 B
constexpr size_t OFF_CAND = 524304;          // 2*4096 u64  = 65,536 B
// fast-path act planes (only if ws_size >= WS_NEED_FAST):
constexpr size_t OFF_XH   = 46104576;   // [b][d][h][oct][w][8] f16 = 4,194,304 B
constexpr size_t OFF_XL   = 50298880;   // 4,194,304 B
constexpr size_t WS_NEED_FAST = 54493184;

// ---------------- fused weight transforms (one launch) ----------------
// Wg: per (nt,tap,cihalf): 32 KB block = 128 rows (local cout) x 256 B.
// Row n holds 64 hi f16 then 64 lo f16, as 16 columns of 16 B, stored
// column = logical ^ (n&15) (4-bit XOR swizzle; bijective). EXACT LDS image
// k_conv wants -> global_load_lds copies linearly (pre-swizzled-source,
// m173); ds_read_b128 frag reads measured 0 bank conflicts (R15-R19).
// f16 split with x1024 scale: wh+wl = 1024*w, residual floor ~2^-22 rel.
#define NT_WT   (27 * 128 * 512)
#define NT_WHT  (512 * 80)
__global__ void k_wtrans(const float* __restrict__ Wc, u16* __restrict__ Wg,
                         const float* __restrict__ Wcls, const float* __restrict__ Wbb,
                         float* __restrict__ Wht) {
    int e = blockIdx.x * blockDim.x + threadIdx.x;
    if (e < NT_WT) {
        const int k    = e & 63;
        const int n    = (e >> 6) & 127;
        const int half = (e >> 13) & 1;
        const int rest = e >> 14;            // nt*27 + tap, [0,108)
        const int co = (rest / 27) * 128 + n;
        const int ci = half * 64 + k;
        const int tp = rest % 27;
        const float v = Wc[(co * 128 + ci) * 27 + tp] * 1024.f;
        const _Float16 h = (_Float16)v;
        const _Float16 l = (_Float16)(v - (float)h);
        char* rb = (char*)Wg + (((size_t)(rest * 2 + half)) << 15) + n * 256;
        const int hcol = (k >> 3) ^ (n & 15);
        const int lcol = ((k >> 3) | 8) ^ (n & 15);
        const int kb = (k & 7) << 1;
        *(u16*)(rb + (hcol << 4) + kb) = __builtin_bit_cast(unsigned short, h);
        *(u16*)(rb + (lcol << 4) + kb) = __builtin_bit_cast(unsigned short, l);
        return;
    }
    e -= NT_WT;
    if (e >= NT_WHT) return;
    int q = e % 80;
    int c = e / 80;
    int og = q / 10, k = q % 10;
    int o = og * 9 + k;
    float v = 0.f;
    if (k < 9) v = (o < 18) ? Wcls[o * 512 + c] : Wbb[(o - 18) * 512 + c];
    Wht[e] = v;
}

// ---------------- input transpose + f16 hi/lo split (fast path only) ----------------
// base_feat [b][128ci][8][32][32] f32 -> xh/xl [b][8][32][oct16][w32][8ci] f16.
// Octet-interleaved so k_conv_f frag loads are 512B-contiguous per 32 lanes.
// Values: h = f16(1024*a), l = f16(1024*a - h) — BIT-IDENTICAL formula to
// R14-R19.
__global__ __launch_bounds__(256) void k_split(const float* __restrict__ in,
                                               u16* __restrict__ xh, u16* __restrict__ xl) {
    __shared__ float t[128][33];
    const int blk = blockIdx.x;                  // b*256 + d*32 + h
    const int b = blk >> 8, d = (blk >> 5) & 7, h = blk & 31;
    const int tid = threadIdx.x;
    const float* src = in + ((size_t)b << 20) + d * 1024 + h * 32;
    #pragma unroll
    for (int i = 0; i < 16; ++i) {
        const int e = tid + i * 256;
        const int ci = e >> 5, w = e & 31;
        t[ci][w] = src[(size_t)ci * 8192 + w];
    }
    __syncthreads();
    const size_t ob = (size_t)((b * 8 + d) * 32 + h) * 4096;   // 4096 u16/plane
    #pragma unroll
    for (int i = 0; i < 2; ++i) {
        const int e = tid + i * 256;         // 512 (oct,w) pairs
        const int oct = e >> 5, w = e & 31;
        unsigned sh0, sh1, sh2, sh3, sl0, sl1, sl2, sl3;
        #define SPL2(C, SH, SL) { \
            const float va_ = t[oct * 8 + 2*(C)][w] * 1024.f; \
            const float vb_ = t[oct * 8 + 2*(C)+1][w] * 1024.f; \
            const _Float16 ha_ = (_Float16)va_, hb_ = (_Float16)vb_; \
            const _Float16 la_ = (_Float16)(va_ - (float)ha_); \
            const _Float16 lb_ = (_Float16)(vb_ - (float)hb_); \
            SH = (unsigned)__builtin_bit_cast(unsigned short, ha_) | \
                 ((unsigned)__builtin_bit_cast(unsigned short, hb_) << 16); \
            SL = (unsigned)__builtin_bit_cast(unsigned short, la_) | \
                 ((unsigned)__builtin_bit_cast(unsigned short, lb_) << 16); }
        SPL2(0, sh0, sl0) SPL2(1, sh1, sl1) SPL2(2, sh2, sl2) SPL2(3, sh3, sl3)
        #undef SPL2
        uint32x4 vh = {sh0, sh1, sh2, sh3};
        uint32x4 vl = {sl0, sl1, sl2, sl3};
        *(uint32x4*)(xh + ob + (size_t)e * 8) = vh;   // 16B per (oct,w), coalesced
        *(uint32x4*)(xl + ob + (size_t)e * 8) = vl;
    }
}

// ---------------- conv3d 3x3x3 + bias + relu: MFMA implicit GEMM ----------------
// Shared pieces (both conv variants): MFMA core, W staging, epilogue.
#define MFMA(A, B, C) __builtin_amdgcn_mfma_f32_32x32x16_f16((A), (B), (C), 0, 0, 0)
#define Z16 {0.f,0.f,0.f,0.f,0.f,0.f,0.f,0.f,0.f,0.f,0.f,0.f,0.f,0.f,0.f,0.f}

// Stage S weights (32 KB) -> LDS buffer BUF via global_load_lds, linear copy.
#define WISSUE(S, BUF) { \
    const int tap_ = t0 + ((S) >> 1); \
    const char* gw_ = WgB + (((size_t)((nt * 27 + tap_) * 2 + ((S) & 1))) << 15) \
                    + (wv << 13) + ln16; \
    char* lb_ = smem + ((BUF) << 15) + (wv << 13); \
    _Pragma("unroll") \
    for (int j_ = 0; j_ < 8; ++j_) \
        __builtin_amdgcn_global_load_lds( \
            (const __attribute__((address_space(1))) void*)(gw_ + (j_ << 10)), \
            (__attribute__((address_space(3))) void*)(lb_ + (j_ << 10)), 16, 0, 0); }

// 12 MFMAs as 3 rounds of 4 independent acc-chains (dep-stall-free issue);
// per-acc product order (wh,BH)->(wh,BL)->(wl,BH) preserved -> bit-identical.
#define KKSTEP(KK, BH0, BL0, BH1, BL1) { \
    const int ch_ = ((((KK) << 1) + cq) ^ rsw) << 4; \
    const int cl_ = (((((KK) << 1) + cq) | 8) ^ rsw) << 4; \
    const char* r0_ = wb_ + (rm0 << 8); \
    const char* r1_ = wb_ + (rm1 << 8); \
    const f16x8 wh0 = *(const f16x8*)(r0_ + ch_); \
    const f16x8 wl0 = *(const f16x8*)(r0_ + cl_); \
    const f16x8 wh1 = *(const f16x8*)(r1_ + ch_); \
    const f16x8 wl1 = *(const f16x8*)(r1_ + cl_); \
    acc00 = MFMA(wh0, BH0, acc00); \
    acc01 = MFMA(wh0, BH1, acc01); \
    acc10 = MFMA(wh1, BH0, acc10); \
    acc11 = MFMA(wh1, BH1, acc11); \
    acc00 = MFMA(wh0, BL0, acc00); \
    acc01 = MFMA(wh0, BL1, acc01); \
    acc10 = MFMA(wh1, BL0, acc10); \
    acc11 = MFMA(wh1, BL1, acc11); \
    acc00 = MFMA(wl0, BH0, acc00); \
    acc01 = MFMA(wl0, BH1, acc01); \
    acc10 = MFMA(wl1, BH0, acc10); \
    acc11 = MFMA(wl1, BH1, acc11); }

// acc = 2^20 * conv -> unscale exactly, + bias, relu
#define EPI(ACC, MI, NI) { \
    const int coB_ = co0 + (wm << 6) + ((MI) << 5) + hl4; \
    const int pt_  = p0 + (wn << 6) + ((NI) << 5) + l31; \
    _Pragma("unroll") \
    for (int g_ = 0; g_ < 4; ++g_) { \
        _Pragma("unroll") \
        for (int q_ = 0; q_ < 4; ++q_) { \
            const int co_ = coB_ + (g_ << 3) + q_; \
            const float v_ = ACC[g_ * 4 + q_] * 9.5367431640625e-07f + bconv[co_]; \
            x[((size_t)((b << 9) + co_) << 13) + pt_] = fmaxf(v_, 0.f); \
        } } }

// ======== FAST conv: acts pre-split, B-frags = coalesced 16B loads ========
// Octet layout: elem = plane(b,id,h2)*4096 + oct*256 + w*8 + c. One FLD:
// lanes (w=0..31, cq) read 2x512B contiguous. KK offset = (KK*2)<<8 elems
// = 1KB, folds into the 13-bit inst offset.
#define FLD(N, KK, BH, BL) { \
    const int h2_ = hb_ + (N); \
    const bool ok_ = okw_ && ((unsigned)h2_ < 32u); \
    const size_t ix_ = sbase_ + ((size_t)(h2_ & 31) << 12); \
    const f16x8 vh_ = *(const f16x8*)(xh + ix_ + ((KK) << 9)); \
    const f16x8 vl_ = *(const f16x8*)(xl + ix_ + ((KK) << 9)); \
    BH = ok_ ? vh_ : fz8; \
    BL = ok_ ? vl_ : fz8; }

#define ALOADF(S, P) { \
    const int tap_ = t0 + ((S) >> 1); \
    const int kd_ = tap_ / 9, kh_ = (tap_ / 3) % 3, kw_ = tap_ % 3; \
    const int id_ = d0 + kd_ - 1; \
    const int w2_ = l31 + kw_ - 1; \
    const bool okw_ = (unsigned)w2_ < 32u; \
    const int hb_ = h0 + (wn << 1) + kh_ - 1; \
    const int oc0_ = (((S) & 1) << 3) + cq; \
    const size_t sbase_ = (((size_t)((b << 3) + id_)) << 17) + (oc0_ << 8) + ((w2_ & 31) << 3); \
    FLD(0, 0, P##h00, P##l00) FLD(0, 1, P##h01, P##l01) \
    FLD(0, 2, P##h02, P##l02) FLD(0, 3, P##h03, P##l03) \
    FLD(1, 0, P##h10, P##l10) FLD(1, 1, P##h11, P##l11) \
    FLD(1, 2, P##h12, P##l12) FLD(1, 3, P##h13, P##l13) }

#define COMPUTEF(BUF, P) { \
    const char* wb_ = smem + ((BUF) << 15); \
    KKSTEP(0, P##h00, P##l00, P##h10, P##l10) \
    KKSTEP(1, P##h01, P##l01, P##h11, P##l11) \
    KKSTEP(2, P##h02, P##l02, P##h12, P##l12) \
    KKSTEP(3, P##h03, P##l03, P##h13, P##l13) }

// Counted waits (T4): vmcnt order per stage is pinned [8 W][16 acts] by a
// sched_barrier between WISSUE and ALOADF. No other vmem ops in the loop.
#define VMCNT24 asm volatile("s_waitcnt vmcnt(24)" ::: "memory");
#define VMCNT16 asm volatile("s_waitcnt vmcnt(16)" ::: "memory");
#define VMCNT0  asm volatile("s_waitcnt vmcnt(0)"  ::: "memory");
#define SBAR    __builtin_amdgcn_s_barrier();
#define SCHED0  __builtin_amdgcn_sched_barrier(0);

__global__ __launch_bounds__(256, 2) void k_conv_f(const u16* __restrict__ xh,
                                                   const u16* __restrict__ xl,
                                                   const u16* __restrict__ Wg,
                                                   const float* __restrict__ bconv,
                                                   float* __restrict__ x) {
    __shared__ __align__(16) char smem[65536];   // W double-buffer: 2 x 32 KB
    const int tid  = threadIdx.x;
    const int bx   = blockIdx.x;        // 64 spatial tiles (128 pts each)
    const int nt   = blockIdx.y;        // 4 cout tiles of 128
    const int b    = blockIdx.z;
    const int p0   = bx << 7;
    const int d0   = bx >> 3;
    const int h0   = (bx & 7) << 2;
    const int co0  = nt << 7;

    const int lane = tid & 63;
    const int wv   = tid >> 6;          // wave id
    const int wm   = wv & 1;            // cout 64-half
    const int wn   = wv >> 1;           // pt 64-half
    const int l31  = lane & 31;         // frag row/col
    const int cq   = lane >> 5;         // frag k-octet half
    const int hl4  = cq << 2;           // C/D row group
    const int rsw  = l31 & 15;          // W-row XOR swizzle key
    const int rm0  = (wm << 6) + l31;   // weight LDS rows (256 B each)
    const int rm1  = rm0 + 32;
    const int ln16 = lane << 4;

    const int t0   = (d0 == 0) ? 9 : 0;
    const int nTap = 27 - (((d0 == 0) || (d0 == 7)) ? 9 : 0);
    const int NS   = nTap * 2;          // stages (EVEN: 54 or 36)

    const char* WgB = (const char*)Wg;
    const f16x8 fz8 = {(_Float16)0.f, (_Float16)0.f, (_Float16)0.f, (_Float16)0.f,
                       (_Float16)0.f, (_Float16)0.f, (_Float16)0.f, (_Float16)0.f};

    f16x8 Ah00, Al00, Ah01, Al01, Ah02, Al02, Ah03, Al03,
          Ah10, Al10, Ah11, Al11, Ah12, Al12, Ah13, Al13;
    f16x8 Bh00, Bl00, Bh01, Bl01, Bh02, Bl02, Bh03, Bl03,
          Bh10, Bl10, Bh11, Bl11, Bh12, Bl12, Bh13, Bl13;
    f32x16 acc00 = Z16, acc01 = Z16, acc10 = Z16, acc11 = Z16;

    // Prologue: W(0)->buf0 (8 loads), acts(0)->A (16 loads), pinned order.
    WISSUE(0, 0)
    SCHED0
    ALOADF(0, A)
    VMCNT16                             // own W(0) landed (acts(0) may fly)
    SBAR                                // all waves' W(0) in LDS

    for (int s = 0; s < NS; s += 2) {
        // ---- even stage s: buf0 + frags A; prefetch s+1 (buf1 + B) ----
        WISSUE(s + 1, 1)                // safe: buf1 last read 2 stages ago,
        SCHED0                          //       barrier'd after that read
        ALOADF(s + 1, B)
        VMCNT24                         // acts(s) done (oldest 16 of 40)
        SCHED0
        COMPUTEF(0, A)
        VMCNT16                         // W(s+1) landed (oldest 8 of 24)
        SBAR                            // all waves: W(s+1) visible; buf0 free
        // ---- odd stage s+1: buf1 + frags B; prefetch s+2 (buf0 + A) ----
        if (s + 2 < NS) {
            WISSUE(s + 2, 0)
            SCHED0
            ALOADF(s + 2, A)
            VMCNT24                     // acts(s+1) done
        } else {
            VMCNT0                      // tail: acts(s+1) done
        }
        SCHED0
        COMPUTEF(1, B)
        if (s + 2 < NS) {
            VMCNT16                     // W(s+2) landed
            SBAR                        // buf1 free for next WISSUE(s+3,1)
        }
    }

    EPI(acc00, 0, 0)
    EPI(acc01, 0, 1)
    EPI(acc10, 1, 0)
    EPI(acc11, 1, 1)
}

// ======== FALLBACK conv (exact R16): in-kernel split, pipelined ========
// Dormant (R18/R19 confirmed ws >= WS_NEED_FAST) but kept as the safety net.
// Reads base_feat directly — unaffected by the xh/xl layout change.
#define PK2(YA, YB, UH, UL) { \
    const float sa_ = (YA) * 1024.f, sb_ = (YB) * 1024.f; \
    const _Float16 ha_ = (_Float16)sa_, hb_ = (_Float16)sb_; \
    const _Float16 la_ = (_Float16)(sa_ - (float)ha_); \
    const _Float16 lb_ = (_Float16)(sb_ - (float)hb_); \
    UH = (unsigned)__builtin_bit_cast(unsigned short, ha_) | \
         ((unsigned)__builtin_bit_cast(unsigned short, hb_) << 16); \
    UL = (unsigned)__builtin_bit_cast(unsigned short, la_) | \
         ((unsigned)__builtin_bit_cast(unsigned short, lb_) << 16); }

#define BLDI(N, KK) { \
    const int h2_ = hb_ + (N); \
    const bool ok_ = okw_ && ((unsigned)h2_ < 32u); \
    const float* ap_ = in + (((size_t)(cb0_ + ((KK) << 4))) << 13) + spo_ + (h2_ << 5); \
    y[N][KK][0] = ok_ ? ap_[0]     : 0.f; \
    y[N][KK][1] = ok_ ? ap_[8192]  : 0.f; \
    y[N][KK][2] = ok_ ? ap_[16384] : 0.f; \
    y[N][KK][3] = ok_ ? ap_[24576] : 0.f; \
    y[N][KK][4] = ok_ ? ap_[32768] : 0.f; \
    y[N][KK][5] = ok_ ? ap_[40960] : 0.f; \
    y[N][KK][6] = ok_ ? ap_[49152] : 0.f; \
    y[N][KK][7] = ok_ ? ap_[57344] : 0.f; }

#define ALOADISS(S) { \
    const int tap_ = t0 + ((S) >> 1); \
    const int kd_ = tap_ / 9, kh_ = (tap_ / 3) % 3, kw_ = tap_ % 3; \
    const int id_ = d0 + kd_ - 1; \
    const int w2_ = l31 + kw_ - 1; \
    const bool okw_ = (unsigned)w2_ < 32u; \
    const int hb_ = h0 + (wn << 1) + kh_ - 1; \
    const int cb0_ = b * CIN + (((S) & 1) << 6) + (cq << 3); \
    const long long spo_ = ((long long)id_ << 10) + w2_; \
    BLDI(0, 0) BLDI(0, 1) BLDI(0, 2) BLDI(0, 3) \
    BLDI(1, 0) BLDI(1, 1) BLDI(1, 2) BLDI(1, 3) }

#define CVTFRAG(N, KK, BH, BL) { \
    unsigned uh0_, uh1_, uh2_, uh3_, ul0_, ul1_, ul2_, ul3_; \
    PK2(y[N][KK][0], y[N][KK][1], uh0_, ul0_) \
    PK2(y[N][KK][2], y[N][KK][3], uh1_, ul1_) \
    PK2(y[N][KK][4], y[N][KK][5], uh2_, ul2_) \
    PK2(y[N][KK][6], y[N][KK][7], uh3_, ul3_) \
    { uint32x4 th_ = {uh0_, uh1_, uh2_, uh3_}; BH = __builtin_bit_cast(f16x8, th_); } \
    { uint32x4 tl_ = {ul0_, ul1_, ul2_, ul3_}; BL = __builtin_bit_cast(f16x8, tl_); } }

#define CVTALL() { \
    CVTFRAG(0, 0, bh00, bl00) CVTFRAG(0, 1, bh01, bl01) \
    CVTFRAG(0, 2, bh02, bl02) CVTFRAG(0, 3, bh03, bl03) \
    CVTFRAG(1, 0, bh10, bl10) CVTFRAG(1, 1, bh11, bl11) \
    CVTFRAG(1, 2, bh12, bl12) CVTFRAG(1, 3, bh13, bl13) }

#define COMPUTE(BUF) { \
    const char* wb_ = smem + ((BUF) << 15); \
    KKSTEP(0, bh00, bl00, bh10, bl10) \
    KKSTEP(1, bh01, bl01, bh11, bl11) \
    KKSTEP(2, bh02, bl02, bh12, bl12) \
    KKSTEP(3, bh03, bl03, bh13, bl13) }

__global__ __launch_bounds__(256, 2) void k_conv(const float* __restrict__ in,
                                                 const u16* __restrict__ Wg,
                                                 const float* __restrict__ bconv,
                                                 float* __restrict__ x) {
    __shared__ __align__(16) char smem[65536];   // W double-buffer: 2 x 32 KB
    const int tid  = threadIdx.x;
    const int bx   = blockIdx.x;
    const int nt   = blockIdx.y;
    const int b    = blockIdx.z;
    const int p0   = bx << 7;
    const int d0   = bx >> 3;
    const int h0   = (bx & 7) << 2;
    const int co0  = nt << 7;

    const int lane = tid & 63;
    const int wv   = tid >> 6;
    const int wm   = wv & 1;
    const int wn   = wv >> 1;
    const int l31  = lane & 31;
    const int cq   = lane >> 5;
    const int hl4  = cq << 2;
    const int rsw  = l31 & 15;
    const int rm0  = (wm << 6) + l31;
    const int rm1  = rm0 + 32;
    const int ln16 = lane << 4;

    const int t0   = (d0 == 0) ? 9 : 0;
    const int nTap = 27 - (((d0 == 0) || (d0 == 7)) ? 9 : 0);
    const int NS   = nTap * 2;

    const char* WgB = (const char*)Wg;

    float y[2][4][8];
    f16x8 bh00, bh01, bh02, bh03, bh10, bh11, bh12, bh13;
    f16x8 bl00, bl01, bl02, bl03, bl10, bl11, bl12, bl13;
    f32x16 acc00 = Z16, acc01 = Z16, acc10 = Z16, acc11 = Z16;

    WISSUE(0, 0)
    ALOADISS(0)
    __syncthreads();

    for (int s = 0; s < NS; ++s) {
        if (s + 1 < NS) { WISSUE(s + 1, (s + 1) & 1) }
        CVTALL()
        __builtin_amdgcn_sched_barrier(0);
        if (s + 1 < NS) { ALOADISS(s + 1) }
        __builtin_amdgcn_sched_barrier(0);
        COMPUTE(s & 1)
        __syncthreads();
    }

    EPI(acc00, 0, 0)
    EPI(acc01, 0, 1)
    EPI(acc10, 1, 0)
    EPI(acc11, 1, 1)
}

// ---------------- heads GEMM + score/box epilogue + fused score histogram ----------------
// R12 form (measured best): unchanged.
__global__ __launch_bounds__(256) void k_heads(const float* __restrict__ x,
                                               const float* __restrict__ Wht,
                                               const float* __restrict__ bcls,
                                               const float* __restrict__ bbb,
                                               const float* __restrict__ iminfo,
                                               float* __restrict__ scores,
                                               float* __restrict__ boxes,
                                               unsigned int* __restrict__ hist) {
    __shared__ __align__(16) float smx[4096];    // x chunk [ch32][pt128]  16 KB
    __shared__ __align__(16) float Whs[2560];    // weight chunk [kk32][80] 10 KB
    __shared__ __align__(16) float ex[10240];    // exchange [pt128][80]    40 KB
    const int tid = threadIdx.x;
    const int p0  = blockIdx.x * 128;
    const int b   = blockIdx.y;
    const int pl  = tid & 31;     // 32 point-lanes, 4 consecutive points each
    const int og  = tid >> 5;     // 8 output groups of 9

    float acc[4][9] = {};

    for (int cc = 0; cc < 512; cc += 32) {
        __syncthreads();
        #pragma unroll
        for (int i = 0; i < 4; ++i) {
            int e4 = tid + i * 256;          // 1024 float4s
            int ch = e4 >> 5;
            int pt4 = (e4 & 31) * 4;
            *(float4*)&smx[ch * 128 + pt4] =
                *(const float4*)&x[((size_t)(b * COUT + cc + ch) << 13) + p0 + pt4];
        }
        #pragma unroll
        for (int i = 0; i < 10; ++i) {
            int e = tid + i * 256;
            Whs[e] = Wht[cc * 80 + e];
        }
        __syncthreads();
        for (int kk = 0; kk < 32; ++kk) {
            float4 a4 = *(const float4*)&smx[kk * 128 + pl * 4];
            const float* wp = &Whs[kk * 80 + og * 10];
            float2 w0 = *(const float2*)(wp);
            float2 w1 = *(const float2*)(wp + 2);
            float2 w2 = *(const float2*)(wp + 4);
            float2 w3 = *(const float2*)(wp + 6);
            float  w8 = wp[8];
            float wv[9] = {w0.x, w0.y, w1.x, w1.y, w2.x, w2.y, w3.x, w3.y, w8};
            #pragma unroll
            for (int k = 0; k < 9; ++k) {
                float wk = wv[k];
                acc[0][k] += a4.x * wk;
                acc[1][k] += a4.y * wk;
                acc[2][k] += a4.z * wk;
                acc[3][k] += a4.w * wk;
            }
        }
    }

    __syncthreads();
    #pragma unroll
    for (int pi = 0; pi < 4; ++pi)
        #pragma unroll
        for (int k = 0; k < 9; ++k)
            ex[(pl * 4 + pi) * 80 + og * 10 + k] = acc[pi][k];
    __syncthreads();

    if (tid < 128) {
        const int p = p0 + tid;
        float v[72];
        #pragma unroll
        for (int og2 = 0; og2 < 8; ++og2)
            #pragma unroll
            for (int k = 0; k < 9; ++k)
                v[og2 * 9 + k] = ex[tid * 80 + og2 * 10 + k];

        const float im0 = iminfo[b * 3 + 0], im1 = iminfo[b * 3 + 1], im2 = iminfo[b * 3 + 2];
        const float hix = im2 - 1.f, hiy = im1 - 1.f, hiz = im0 - 1.f;
        const int d = p >> 10, h = (p >> 5) & 31, w = p & 31;
        const float sx = w * 8.f, sy = h * 8.f, sz = d * 8.f;

        #pragma unroll 1
        for (int a = 0; a < 9; ++a) {
            float c0 = v[a] + bcls[a];
            float c1 = v[9 + a] + bcls[9 + a];
            float m  = fmaxf(c0, c1);
            float e0 = expf(c0 - m), e1 = expf(c1 - m);
            float sc = e1 / (e0 + e1);
            scores[b * NANCH + p * 9 + a] = sc;
            atomicAdd(&hist[b * 65536 + (__float_as_uint(sc) >> 16)], 1u);

            float aw = (float)(32 << (a % 3));                 // x,y size = 8*SCALES
            float ad = aw * 0.5f * (float)(1 << (a / 3));      // z size = aw*RATIOS
            float ax1 = sx + 3.5f - 0.5f * (aw - 1.f);
            float ax2 = sx + 3.5f + 0.5f * (aw - 1.f);
            float ay1 = sy + 3.5f - 0.5f * (aw - 1.f);
            float ay2 = sy + 3.5f + 0.5f * (aw - 1.f);
            float az1 = sz + 3.5f - 0.5f * (ad - 1.f);
            float az2 = sz + 3.5f + 0.5f * (ad - 1.f);
            float ww_ = ax2 - ax1 + 1.f, hh_ = ay2 - ay1 + 1.f, dd_ = az2 - az1 + 1.f;
            float cx = ax1 + 0.5f * ww_, cy = ay1 + 0.5f * hh_, cz = az1 + 0.5f * dd_;

            const float* dv = &v[18 + a * 6];
            float dx = dv[0] + bbb[a * 6 + 0];
            float dy = dv[1] + bbb[a * 6 + 1];
            float dz = dv[2] + bbb[a * 6 + 2];
            float dw = dv[3] + bbb[a * 6 + 3];
            float dh = dv[4] + bbb[a * 6 + 4];
            float dd2 = dv[5] + bbb[a * 6 + 5];
            float pcx = dx * ww_ + cx, pcy = dy * hh_ + cy, pcz = dz * dd_ + cz;
            float pw = expf(dw) * ww_, ph = expf(dh) * hh_, pd = expf(dd2) * dd_;
            float x1 = fminf(fmaxf(pcx - 0.5f * pw, 0.f), hix);
            float y1 = fminf(fmaxf(pcy - 0.5f * ph, 0.f), hiy);
            float z1 = fminf(fmaxf(pcz - 0.5f * pd, 0.f), hiz);
            float x2 = fminf(fmaxf(pcx + 0.5f * pw, 0.f), hix);
            float y2 = fminf(fmaxf(pcy + 0.5f * ph, 0.f), hiy);
            float z2 = fminf(fmaxf(pcz + 0.5f * pd, 0.f), hiz);
            float* bp = &boxes[(size_t)(b * NANCH + p * 9 + a) * 6];
            bp[0] = x1; bp[1] = y1; bp[2] = z1; bp[3] = x2; bp[4] = y2; bp[5] = z2;
        }
    }
}

// ---------------- fused cutoff + compact (one block per batch) ----------------
__global__ __launch_bounds__(1024) void k_cutcompact(const float* __restrict__ scores,
                                                     const unsigned int* __restrict__ hist,
                                                     unsigned long long* __restrict__ cand) {
    __shared__ unsigned int cs[1024], scan[1024];
    __shared__ unsigned int sh_cut, sh_pos;
    const int b = blockIdx.x, tid = threadIdx.x;
    const unsigned int* h = hist + b * 65536;
    unsigned int s = 0;
    for (int i = 0; i < 64; ++i) s += h[tid * 64 + i];
    cs[tid] = s; scan[tid] = s;
    if (tid == 0) sh_pos = 0;
    __syncthreads();
    for (int d = 1; d < 1024; d <<= 1) {           // scan[c] -> sum_{c'>=c} cs[c']
        unsigned int v = scan[tid];
        unsigned int add = (tid + d < 1024) ? scan[tid + d] : 0u;
        __syncthreads();
        scan[tid] = v + add;
        __syncthreads();
    }
    unsigned int above = (tid + 1 < 1024) ? scan[tid + 1] : 0u;   // strictly above this chunk
    if (above < PRE && above + cs[tid] >= PRE) {   // exactly one thread
        unsigned int cum = above;
        for (int x = tid * 64 + 63; x >= tid * 64; --x) {
            cum += h[x];
            if (cum >= PRE) { sh_cut = (unsigned int)x; break; }
        }
    }
    __syncthreads();
    const unsigned int cut = sh_cut;
    const float* sc = scores + b * NANCH;
    for (int i = tid; i < NANCH; i += 1024) {
        unsigned int u = __float_as_uint(sc[i]);
        if ((u >> 16) >= cut) {
            unsigned int pos = atomicAdd(&sh_pos, 1u);
            if (pos < CAP) cand[b * CAP + pos] = ((unsigned long long)(~u) << 32) | (unsigned)i;
        }
    }
    __syncthreads();
    const unsigned int cnt = (sh_pos < CAP) ? sh_pos : CAP;
    for (int i = (int)cnt + tid; i < CAP; i += 1024)
        cand[b * CAP + i] = ~0ull;
}

// bitonic sort CAP keys asc (key = ~score_bits || idx => score desc, idx asc);
// first 2048 are the sorted top-2048; gather their boxes.
__global__ __launch_bounds__(1024) void k_sort2(const unsigned long long* __restrict__ cand,
                                                const float* __restrict__ boxes,
                                                float* __restrict__ sboxes) {
    __shared__ unsigned long long sk[CAP];
    const int b = blockIdx.x, tid = threadIdx.x;
    for (int i = tid; i < CAP; i += 1024) sk[i] = cand[b * CAP + i];
    __syncthreads();
    for (int k = 2; k <= CAP; k <<= 1) {
        for (int j = k >> 1; j > 0; j >>= 1) {
            #pragma unroll 1
            for (int i = tid; i < CAP; i += 1024) {
                int ixj = i ^ j;
                if (ixj > i) {
                    unsigned long long va = sk[i], vb = sk[ixj];
                    bool up = ((i & k) == 0);
                    if ((va > vb) == up) { sk[i] = vb; sk[ixj] = va; }
                }
            }
            __syncthreads();
        }
    }
    for (int r = tid; r < PRE; r += 1024) {
        unsigned int n = (unsigned int)(sk[r] & 0xFFFFFFFFull);
        const float* src = &boxes[(size_t)(b * NANCH + (int)n) * 6];
        float* dst = &sboxes[(size_t)(b * PRE + r) * 6];
        #pragma unroll
        for (int c = 0; c < 6; ++c) dst[c] = src[c];
    }
}

// suppression bitmask (upper triangle only): mask[b][i][w] bit j <=> j>i && IoU>0.7
__global__ __launch_bounds__(256) void k_mask(const float* __restrict__ sboxes,
                                              unsigned long long* __restrict__ mask) {
    if (blockIdx.y < blockIdx.x) return;   // j0 < i0: never read (k_nms gates by word)
    __shared__ float rb[64 * 6], cb[64 * 6];
    const int i0 = blockIdx.x * 64, j0 = blockIdx.y * 64, b = blockIdx.z;
    const int tid = threadIdx.x;
    for (int e = tid; e < 384; e += 256) {
        rb[e] = sboxes[(size_t)(b * PRE + i0) * 6 + e];
        cb[e] = sboxes[(size_t)(b * PRE + j0) * 6 + e];
    }
    __syncthreads();
    const int wave = tid >> 6, lane = tid & 63;
    const float bx1 = cb[lane * 6 + 0], by1 = cb[lane * 6 + 1], bz1 = cb[lane * 6 + 2];
    const float bx2 = cb[lane * 6 + 3], by2 = cb[lane * 6 + 4], bz2 = cb[lane * 6 + 5];
    const float vb = (bx2 - bx1 + 1.f) * (by2 - by1 + 1.f) * (bz2 - bz1 + 1.f);
    const int j = j0 + lane;
    for (int rr = 0; rr < 16; ++rr) {
        const int il = wave * 16 + rr;
        const int i = i0 + il;
        float ax1 = rb[il * 6 + 0], ay1 = rb[il * 6 + 1], az1 = rb[il * 6 + 2];
        float ax2 = rb[il * 6 + 3], ay2 = rb[il * 6 + 4], az2 = rb[il * 6 + 5];
        float va = (ax2 - ax1 + 1.f) * (ay2 - ay1 + 1.f) * (az2 - az1 + 1.f);
        float ix = fmaxf(fminf(ax2, bx2) - fmaxf(ax1, bx1) + 1.f, 0.f);
        float iy = fmaxf(fminf(ay2, by2) - fmaxf(ay1, by1) + 1.f, 0.f);
        float iz = fmaxf(fminf(az2, bz2) - fmaxf(az1, bz1) + 1.f, 0.f);
        float inter = ix * iy * iz;
        float iou = inter / (va + vb - inter);
        bool bit = (j > i) && (iou > NMS_TH);
        unsigned long long word = __ballot(bit);
        if (lane == 0) mask[(size_t)(b * PRE + i) * 32 + (j0 >> 6)] = word;
    }
}

// single-wave greedy NMS scan + ROI output; 8-deep mask-row prefetch.
__global__ __launch_bounds__(64) void k_nms(const unsigned long long* __restrict__ mask,
                                            const float* __restrict__ sboxes,
                                            float* __restrict__ out) {
    const int b = blockIdx.x, lane = threadIdx.x;
    __shared__ int sel[POST];
    unsigned long long keep = ~0ull;          // lane l<32 owns bits [64l,64l+64)
    const int lw = lane & 31;
    const unsigned long long* mrow = mask + (size_t)b * PRE * 32 + lw;
    unsigned long long b0 = mrow[0 * 32], b1 = mrow[1 * 32], b2 = mrow[2 * 32], b3 = mrow[3 * 32];
    unsigned long long b4 = mrow[4 * 32], b5 = mrow[5 * 32], b6 = mrow[6 * 32], b7 = mrow[7 * 32];
    int kcount = 0;

#define NMS_STEP(J, BUF)                                                        \
    {                                                                           \
        int i = i0 + (J);                                                       \
        unsigned long long cur = (lw >= (i >> 6)) ? BUF : 0ull;                 \
        int nr = i0 + 8 + (J);                                                  \
        BUF = (nr < PRE) ? mrow[(size_t)nr * 32] : 0ull;                        \
        unsigned long long kw = __shfl(keep, i >> 6);                           \
        if ((kw >> (i & 63)) & 1ull) {                                          \
            if (lane < 32) keep &= ~cur;                                        \
            if (lane == 0 && kcount < POST) sel[kcount] = i;                    \
            ++kcount;                                                           \
            if (kcount >= POST) goto nms_done;                                  \
        }                                                                       \
    }

    for (int i0 = 0; i0 < PRE; i0 += 8) {
        NMS_STEP(0, b0) NMS_STEP(1, b1) NMS_STEP(2, b2) NMS_STEP(3, b3)
        NMS_STEP(4, b4) NMS_STEP(5, b5) NMS_STEP(6, b6) NMS_STEP(7, b7)
    }
nms_done:
    __syncthreads();
    const int kc = kcount;
    for (int r = lane; r < POST; r += 64) {
        float* op = &out[(size_t)(b * POST + r) * 7];
        op[0] = (float)b;
        if (r < kc) {
            const float* sb = &sboxes[(size_t)(b * PRE + sel[r]) * 6];
            #pragma unroll
            for (int c = 0; c < 6; ++c) op[1 + c] = sb[c];
        } else {
            #pragma unroll
            for (int c = 0; c < 6; ++c) op[1 + c] = 0.f;
        }
    }
#undef NMS_STEP
}

extern "C" void kernel_launch(void* const* d_in, const int* in_sizes, int n_in,
                              void* d_out, int out_size, void* d_ws, size_t ws_size,
                              hipStream_t stream) {
    const float* base_feat = (const float*)d_in[0];
    const float* im_info   = (const float*)d_in[1];
    const float* W_conv    = (const float*)d_in[4];
    const float* b_conv    = (const float*)d_in[5];
    const float* W_cls     = (const float*)d_in[6];
    const float* b_cls     = (const float*)d_in[7];
    const float* W_bbox    = (const float*)d_in[8];
    const float* b_bbox    = (const float*)d_in[9];

    char* ws = (char*)d_ws;
    u16* Wg        = (u16*)(ws + OFF_WT);
    float* Wht     = (float*)(ws + OFF_WHT);
    float* x       = (float*)(ws + OFF_X);
    float* scores  = (float*)(ws + OFF_SC);
    float* boxes   = (float*)(ws + OFF_BX);
    float* sboxes  = (float*)(ws + OFF_SB);
    unsigned long long* mask = (unsigned long long*)(ws + OFF_MK);
    unsigned int* hist = (unsigned int*)(ws + OFF_HIST);
    unsigned long long* cand = (unsigned long long*)(ws + OFF_CAND);
    u16* xh        = (u16*)(ws + OFF_XH);
    u16* xl        = (u16*)(ws + OFF_XL);

    const int NTRANS = NT_WT + NT_WHT;
    k_wtrans<<<(NTRANS + 255) / 256, 256, 0, stream>>>(W_conv, Wg, W_cls, W_bbox, Wht);
    if (ws_size >= WS_NEED_FAST) {
        k_split<<<512, 256, 0, stream>>>(base_feat, xh, xl);
        k_conv_f<<<dim3(64, 4, 2), 256, 0, stream>>>(xh, xl, Wg, b_conv, x);
    } else {
        k_conv<<<dim3(64, 4, 2), 256, 0, stream>>>(base_feat, Wg, b_conv, x);
    }
    // Wg region dead now; zero hist (aliases Wg) AFTER conv, before k_heads.
    hipMemsetAsync(hist, 0, BATCH * 65536 * sizeof(unsigned int), stream);
    k_heads<<<dim3(64, 2), 256, 0, stream>>>(x, Wht, b_cls, b_bbox, im_info, scores, boxes, hist);
    k_cutcompact<<<BATCH, 1024, 0, stream>>>(scores, hist, cand);
    k_sort2<<<BATCH, 1024, 0, stream>>>(cand, boxes, sboxes);
    k_mask<<<dim3(32, 32, 2), 256, 0, stream>>>(sboxes, mask);
    k_nms<<<BATCH, 64, 0, stream>>>(mask, sboxes, (float*)d_out);
}

// Round 11
// 556.331 us; speedup vs baseline: 1.1990x; 1.0014x over previous
//
#include <hip/hip_runtime.h>
#include <stdint.h>

// Problem constants
#define BATCH 2
#define CIN 128
#define COUT 512
#define DD 8
#define PSPAT 8192          // D*H*W
#define NA 9                // anchors per position
#define NANCH 73728         // PSPAT*NA
#define PRE 2048
#define POST 300
#define CAP 4096            // candidate buffer (top-2048 + cutoff-bin ties)
#define NMS_TH 0.7f

typedef unsigned short u16;
typedef _Float16 f16x8 __attribute__((ext_vector_type(8)));
typedef float f32x16 __attribute__((ext_vector_type(16)));
typedef unsigned int uint32x4 __attribute__((ext_vector_type(4)));

// ws layout (byte offsets). Base footprint = proven 46,104,576 B.
// R23 == R21 with the WISSUE LDS-dest divergence FIXED: R21 passed
// per-lane (+ln16) LDS pointer to global_load_lds; the LDS dest must be
// WAVE-UNIFORM (m104/m108 — hw adds lane*16; per-lane offset belongs on the
// global source only). Divergent operand -> possible OOB-LDS/waterfall =
// the one plausible kernel-side container-killer. Now matches R20's proven
// staging form exactly. (R21/R22 benches: "container failed twice", no
// compile/test output — likely broker outage, but de-risking anyway.)
// R21 design: conv re-tiled 128->64 cout per block (nt=8), 2-wave blocks,
// 16 KB W stages, 32 KB LDS dbuf -> 4-5 INDEPENDENT blocks/CU (was 2
// in-phase 4-wave blocks at 64 KB). R20 diagnosis: stage wall 9k cyc vs
// 3.1k MFMA demand, all pipes idle — overlap failure at 2 blocks/CU.
// Per-wave schedule identical (24 vmem/stage -> same counted vmcnt); same W
// row format+swizzle. + T5 setprio around MFMA cluster (independent blocks
// = role diversity, m191 regime). Act L2 traffic 2x accepted. Numerics
// bit-identical to R14-R20.
constexpr size_t OFF_WT   = 0;          // 216*2 blocks * 16KB = 7,077,888 B (f16 hi/lo image)
constexpr size_t OFF_WHT  = 7077888;    // 512*80 f32       = 163,840 B
constexpr size_t OFF_X    = 7241728;    // 2*512*8192 f32   = 33,554,432 B
constexpr size_t OFF_SC   = 40796160;   // 2*73728 f32      = 589,824 B
constexpr size_t OFF_BX   = 41385984;   // 2*73728*6 f32    = 3,538,944 B
constexpr size_t OFF_SB   = 44957696;   // 2*2048*6 f32     = 98,304 B
constexpr size_t OFF_MK   = 45056000;   // 2*2048*32 u64    = 1,048,576 B  (end 46,104,576)
// selection scratch inside [0, OFF_WT+7MB), used only after conv:
constexpr size_t OFF_HIST = 16;              // 2*65536 u32 = 524,288 B
constexpr size_t OFF_CAND = 524304;          // 2*4096 u64  = 65,536 B
// act planes:
constexpr size_t OFF_XH   = 46104576;   // [b][d][h][oct][w][8] f16 = 4,194,304 B
constexpr size_t OFF_XL   = 50298880;   // 4,194,304 B (end 54,493,184)

// ---------------- fused weight transforms (one launch) ----------------
// Wg: per (nt8,tap,cihalf): 16 KB block = 64 rows (local cout) x 256 B.
// Row n holds 64 hi f16 then 64 lo f16, as 16 columns of 16 B, stored
// column = logical ^ (n&15) (4-bit XOR swizzle; bijective). EXACT LDS image
// k_conv_f wants -> global_load_lds copies linearly (pre-swizzled-source,
// m173); ds_read_b128 frag reads measured 0 bank conflicts (R15-R20).
// f16 split with x1024 scale: wh+wl = 1024*w, residual floor ~2^-22 rel.
#define NT_WT   (27 * 128 * 512)
#define NT_WHT  (512 * 80)
__global__ void k_wtrans(const float* __restrict__ Wc, u16* __restrict__ Wg,
                         const float* __restrict__ Wcls, const float* __restrict__ Wbb,
                         float* __restrict__ Wht) {
    int e = blockIdx.x * blockDim.x + threadIdx.x;
    if (e < NT_WT) {
        const int k    = e & 63;
        const int n    = (e >> 6) & 63;
        const int half = (e >> 12) & 1;
        const int rest = e >> 13;            // nt8*27 + tap, [0,216)
        const int co = (rest / 27) * 64 + n;
        const int ci = half * 64 + k;
        const int tp = rest % 27;
        const float v = Wc[(co * 128 + ci) * 27 + tp] * 1024.f;
        const _Float16 h = (_Float16)v;
        const _Float16 l = (_Float16)(v - (float)h);
        char* rb = (char*)Wg + (((size_t)(rest * 2 + half)) << 14) + n * 256;
        const int hcol = (k >> 3) ^ (n & 15);
        const int lcol = ((k >> 3) | 8) ^ (n & 15);
        const int kb = (k & 7) << 1;
        *(u16*)(rb + (hcol << 4) + kb) = __builtin_bit_cast(unsigned short, h);
        *(u16*)(rb + (lcol << 4) + kb) = __builtin_bit_cast(unsigned short, l);
        return;
    }
    e -= NT_WT;
    if (e >= NT_WHT) return;
    int q = e % 80;
    int c = e / 80;
    int og = q / 10, k = q % 10;
    int o = og * 9 + k;
    float v = 0.f;
    if (k < 9) v = (o < 18) ? Wcls[o * 512 + c] : Wbb[(o - 18) * 512 + c];
    Wht[e] = v;
}

// ---------------- input transpose + f16 hi/lo split ----------------
// base_feat [b][128ci][8][32][32] f32 -> xh/xl [b][8][32][oct16][w32][8ci] f16.
// Octet-interleaved so k_conv_f frag loads are 512B-contiguous per 32 lanes.
// Values: h = f16(1024*a), l = f16(1024*a - h) — BIT-IDENTICAL formula to
// R14-R20.
__global__ __launch_bounds__(256) void k_split(const float* __restrict__ in,
                                               u16* __restrict__ xh, u16* __restrict__ xl) {
    __shared__ float t[128][33];
    const int blk = blockIdx.x;                  // b*256 + d*32 + h
    const int b = blk >> 8, d = (blk >> 5) & 7, h = blk & 31;
    const int tid = threadIdx.x;
    const float* src = in + ((size_t)b << 20) + d * 1024 + h * 32;
    #pragma unroll
    for (int i = 0; i < 16; ++i) {
        const int e = tid + i * 256;
        const int ci = e >> 5, w = e & 31;
        t[ci][w] = src[(size_t)ci * 8192 + w];
    }
    __syncthreads();
    const size_t ob = (size_t)((b * 8 + d) * 32 + h) * 4096;   // 4096 u16/plane
    #pragma unroll
    for (int i = 0; i < 2; ++i) {
        const int e = tid + i * 256;         // 512 (oct,w) pairs
        const int oct = e >> 5, w = e & 31;
        unsigned sh0, sh1, sh2, sh3, sl0, sl1, sl2, sl3;
        #define SPL2(C, SH, SL) { \
            const float va_ = t[oct * 8 + 2*(C)][w] * 1024.f; \
            const float vb_ = t[oct * 8 + 2*(C)+1][w] * 1024.f; \
            const _Float16 ha_ = (_Float16)va_, hb_ = (_Float16)vb_; \
            const _Float16 la_ = (_Float16)(va_ - (float)ha_); \
            const _Float16 lb_ = (_Float16)(vb_ - (float)hb_); \
            SH = (unsigned)__builtin_bit_cast(unsigned short, ha_) | \
                 ((unsigned)__builtin_bit_cast(unsigned short, hb_) << 16); \
            SL = (unsigned)__builtin_bit_cast(unsigned short, la_) | \
                 ((unsigned)__builtin_bit_cast(unsigned short, lb_) << 16); }
        SPL2(0, sh0, sl0) SPL2(1, sh1, sl1) SPL2(2, sh2, sl2) SPL2(3, sh3, sl3)
        #undef SPL2
        uint32x4 vh = {sh0, sh1, sh2, sh3};
        uint32x4 vl = {sl0, sl1, sl2, sl3};
        *(uint32x4*)(xh + ob + (size_t)e * 8) = vh;   // 16B per (oct,w), coalesced
        *(uint32x4*)(xl + ob + (size_t)e * 8) = vl;
    }
}

// ---------------- conv3d 3x3x3 + bias + relu: MFMA implicit GEMM ----------------
// M=cout(64-tile), N=spatial(128 pts: fixed d, 4 h-rows), K=tap*ci.
// f16 2-way split (x1024), 3 products into ONE fp32 accumulator — numerics
// bit-identical to R14-R20. Block = 2 waves: wave wv owns pt-half wn=wv.
#define MFMA(A, B, C) __builtin_amdgcn_mfma_f32_32x32x16_f16((A), (B), (C), 0, 0, 0)
#define Z16 {0.f,0.f,0.f,0.f,0.f,0.f,0.f,0.f,0.f,0.f,0.f,0.f,0.f,0.f,0.f,0.f}

// Stage S weights (16 KB) -> LDS buffer BUF via global_load_lds, linear copy.
// Per wave: 8 instrs x 1 KB = 8 KB; 2 waves cover the 16 KB stage.
// LDS dest is WAVE-UNIFORM (hw adds lane*16); per-lane ln16 on global only.
#define WISSUE(S, BUF) { \
    const int tap_ = t0 + ((S) >> 1); \
    const char* gw_ = WgB + (((size_t)((nt * 27 + tap_) * 2 + ((S) & 1))) << 14) \
                    + (wv << 13) + ln16; \
    char* lb_ = smem + ((BUF) << 14) + (wv << 13); \
    _Pragma("unroll") \
    for (int j_ = 0; j_ < 8; ++j_) \
        __builtin_amdgcn_global_load_lds( \
            (const __attribute__((address_space(1))) void*)(gw_ + (j_ << 10)), \
            (__attribute__((address_space(3))) void*)(lb_ + (j_ << 10)), 16, 0, 0); }

// 12 MFMAs as 3 rounds of 4 independent acc-chains; per-acc product order
// (wh,BH)->(wh,BL)->(wl,BH) preserved -> bit-identical.
#define KKSTEP(KK, BH0, BL0, BH1, BL1) { \
    const int ch_ = ((((KK) << 1) + cq) ^ rsw) << 4; \
    const int cl_ = (((((KK) << 1) + cq) | 8) ^ rsw) << 4; \
    const char* r0_ = wb_ + (rm0 << 8); \
    const char* r1_ = wb_ + (rm1 << 8); \
    const f16x8 wh0 = *(const f16x8*)(r0_ + ch_); \
    const f16x8 wl0 = *(const f16x8*)(r0_ + cl_); \
    const f16x8 wh1 = *(const f16x8*)(r1_ + ch_); \
    const f16x8 wl1 = *(const f16x8*)(r1_ + cl_); \
    acc00 = MFMA(wh0, BH0, acc00); \
    acc01 = MFMA(wh0, BH1, acc01); \
    acc10 = MFMA(wh1, BH0, acc10); \
    acc11 = MFMA(wh1, BH1, acc11); \
    acc00 = MFMA(wh0, BL0, acc00); \
    acc01 = MFMA(wh0, BL1, acc01); \
    acc10 = MFMA(wh1, BL0, acc10); \
    acc11 = MFMA(wh1, BL1, acc11); \
    acc00 = MFMA(wl0, BH0, acc00); \
    acc01 = MFMA(wl0, BH1, acc01); \
    acc10 = MFMA(wl1, BH0, acc10); \
    acc11 = MFMA(wl1, BH1, acc11); }

// acc = 2^20 * conv -> unscale exactly, + bias, relu
#define EPI(ACC, MI, NI) { \
    const int coB_ = co0 + ((MI) << 5) + hl4; \
    const int pt_  = p0 + (wn << 6) + ((NI) << 5) + l31; \
    _Pragma("unroll") \
    for (int g_ = 0; g_ < 4; ++g_) { \
        _Pragma("unroll") \
        for (int q_ = 0; q_ < 4; ++q_) { \
            const int co_ = coB_ + (g_ << 3) + q_; \
            const float v_ = ACC[g_ * 4 + q_] * 9.5367431640625e-07f + bconv[co_]; \
            x[((size_t)((b << 9) + co_) << 13) + pt_] = fmaxf(v_, 0.f); \
        } } }

// B-frags: coalesced 16B loads from octet-interleaved xh/xl. One FLD: lanes
// (w=0..31, cq) read 2x512B contiguous; KK offset = 1KB inst-offset fold.
// Halo: h/w clamped in-plane for the address (&31), value zeroed by cndmask.
#define FLD(N, KK, BH, BL) { \
    const int h2_ = hb_ + (N); \
    const bool ok_ = okw_ && ((unsigned)h2_ < 32u); \
    const size_t ix_ = sbase_ + ((size_t)(h2_ & 31) << 12); \
    const f16x8 vh_ = *(const f16x8*)(xh + ix_ + ((KK) << 9)); \
    const f16x8 vl_ = *(const f16x8*)(xl + ix_ + ((KK) << 9)); \
    BH = ok_ ? vh_ : fz8; \
    BL = ok_ ? vl_ : fz8; }

#define ALOADF(S, P) { \
    const int tap_ = t0 + ((S) >> 1); \
    const int kd_ = tap_ / 9, kh_ = (tap_ / 3) % 3, kw_ = tap_ % 3; \
    const int id_ = d0 + kd_ - 1; \
    const int w2_ = l31 + kw_ - 1; \
    const bool okw_ = (unsigned)w2_ < 32u; \
    const int hb_ = h0 + (wn << 1) + kh_ - 1; \
    const int oc0_ = (((S) & 1) << 3) + cq; \
    const size_t sbase_ = (((size_t)((b << 3) + id_)) << 17) + (oc0_ << 8) + ((w2_ & 31) << 3); \
    FLD(0, 0, P##h00, P##l00) FLD(0, 1, P##h01, P##l01) \
    FLD(0, 2, P##h02, P##l02) FLD(0, 3, P##h03, P##l03) \
    FLD(1, 0, P##h10, P##l10) FLD(1, 1, P##h11, P##l11) \
    FLD(1, 2, P##h12, P##l12) FLD(1, 3, P##h13, P##l13) }

#define COMPUTEF(BUF, P) { \
    const char* wb_ = smem + ((BUF) << 14); \
    __builtin_amdgcn_s_setprio(1); \
    KKSTEP(0, P##h00, P##l00, P##h10, P##l10) \
    KKSTEP(1, P##h01, P##l01, P##h11, P##l11) \
    KKSTEP(2, P##h02, P##l02, P##h12, P##l12) \
    KKSTEP(3, P##h03, P##l03, P##h13, P##l13) \
    __builtin_amdgcn_s_setprio(0); }

// Counted waits (T4): vmcnt order per stage is pinned [8 W][16 acts] by a
// sched_barrier between WISSUE and ALOADF. No other vmem ops in the loop.
#define VMCNT24 asm volatile("s_waitcnt vmcnt(24)" ::: "memory");
#define VMCNT16 asm volatile("s_waitcnt vmcnt(16)" ::: "memory");
#define VMCNT0  asm volatile("s_waitcnt vmcnt(0)"  ::: "memory");
#define SBAR    __builtin_amdgcn_s_barrier();
#define SCHED0  __builtin_amdgcn_sched_barrier(0);

__global__ __launch_bounds__(128, 2) void k_conv_f(const u16* __restrict__ xh,
                                                   const u16* __restrict__ xl,
                                                   const u16* __restrict__ Wg,
                                                   const float* __restrict__ bconv,
                                                   float* __restrict__ x) {
    __shared__ __align__(16) char smem[32768];   // W double-buffer: 2 x 16 KB
    const int tid  = threadIdx.x;
    const int bx   = blockIdx.x;        // 64 spatial tiles (128 pts each)
    const int nt   = blockIdx.y;        // 8 cout tiles of 64
    const int b    = blockIdx.z;
    const int p0   = bx << 7;
    const int d0   = bx >> 3;
    const int h0   = (bx & 7) << 2;
    const int co0  = nt << 6;

    const int lane = tid & 63;
    const int wv   = tid >> 6;          // wave id (0,1)
    const int wn   = wv;                // pt 64-half
    const int l31  = lane & 31;         // frag row/col
    const int cq   = lane >> 5;         // frag k-octet half
    const int hl4  = cq << 2;           // C/D row group
    const int rsw  = l31 & 15;          // W-row XOR swizzle key
    const int rm0  = l31;               // weight LDS rows (256 B each)
    const int rm1  = l31 + 32;
    const int ln16 = lane << 4;

    const int t0   = (d0 == 0) ? 9 : 0;
    const int nTap = 27 - (((d0 == 0) || (d0 == 7)) ? 9 : 0);
    const int NS   = nTap * 2;          // stages (EVEN: 54 or 36)

    const char* WgB = (const char*)Wg;
    const f16x8 fz8 = {(_Float16)0.f, (_Float16)0.f, (_Float16)0.f, (_Float16)0.f,
                       (_Float16)0.f, (_Float16)0.f, (_Float16)0.f, (_Float16)0.f};

    f16x8 Ah00, Al00, Ah01, Al01, Ah02, Al02, Ah03, Al03,
          Ah10, Al10, Ah11, Al11, Ah12, Al12, Ah13, Al13;
    f16x8 Bh00, Bl00, Bh01, Bl01, Bh02, Bl02, Bh03, Bl03,
          Bh10, Bl10, Bh11, Bl11, Bh12, Bl12, Bh13, Bl13;
    f32x16 acc00 = Z16, acc01 = Z16, acc10 = Z16, acc11 = Z16;

    // Prologue: W(0)->buf0 (8 loads), acts(0)->A (16 loads), pinned order.
    WISSUE(0, 0)
    SCHED0
    ALOADF(0, A)
    VMCNT16                             // own W(0) landed (acts(0) may fly)
    SBAR                                // both waves' W(0) in LDS

    for (int s = 0; s < NS; s += 2) {
        // ---- even stage s: buf0 + frags A; prefetch s+1 (buf1 + B) ----
        WISSUE(s + 1, 1)                // safe: buf1 last read 2 stages ago,
        SCHED0                          //       barrier'd after that read
        ALOADF(s + 1, B)
        VMCNT24                         // acts(s) done (oldest 16 of 40)
        SCHED0
        COMPUTEF(0, A)
        VMCNT16                         // W(s+1) landed (oldest 8 of 24)
        SBAR                            // both waves: W(s+1) visible; buf0 free
        // ---- odd stage s+1: buf1 + frags B; prefetch s+2 (buf0 + A) ----
        if (s + 2 < NS) {
            WISSUE(s + 2, 0)
            SCHED0
            ALOADF(s + 2, A)
            VMCNT24                     // acts(s+1) done
        } else {
            VMCNT0                      // tail: acts(s+1) done
        }
        SCHED0
        COMPUTEF(1, B)
        if (s + 2 < NS) {
            VMCNT16                     // W(s+2) landed
            SBAR                        // buf1 free for next WISSUE(s+3,1)
        }
    }

    EPI(acc00, 0, 0)
    EPI(acc01, 0, 1)
    EPI(acc10, 1, 0)
    EPI(acc11, 1, 1)
}

// ---------------- heads GEMM + score/box epilogue + fused score histogram ----------------
// R12 form (measured best): unchanged.
__global__ __launch_bounds__(256) void k_heads(const float* __restrict__ x,
                                               const float* __restrict__ Wht,
                                               const float* __restrict__ bcls,
                                               const float* __restrict__ bbb,
                                               const float* __restrict__ iminfo,
                                               float* __restrict__ scores,
                                               float* __restrict__ boxes,
                                               unsigned int* __restrict__ hist) {
    __shared__ __align__(16) float smx[4096];    // x chunk [ch32][pt128]  16 KB
    __shared__ __align__(16) float Whs[2560];    // weight chunk [kk32][80] 10 KB
    __shared__ __align__(16) float ex[10240];    // exchange [pt128][80]    40 KB
    const int tid = threadIdx.x;
    const int p0  = blockIdx.x * 128;
    const int b   = blockIdx.y;
    const int pl  = tid & 31;     // 32 point-lanes, 4 consecutive points each
    const int og  = tid >> 5;     // 8 output groups of 9

    float acc[4][9] = {};

    for (int cc = 0; cc < 512; cc += 32) {
        __syncthreads();
        #pragma unroll
        for (int i = 0; i < 4; ++i) {
            int e4 = tid + i * 256;          // 1024 float4s
            int ch = e4 >> 5;
            int pt4 = (e4 & 31) * 4;
            *(float4*)&smx[ch * 128 + pt4] =
                *(const float4*)&x[((size_t)(b * COUT + cc + ch) << 13) + p0 + pt4];
        }
        #pragma unroll
        for (int i = 0; i < 10; ++i) {
            int e = tid + i * 256;
            Whs[e] = Wht[cc * 80 + e];
        }
        __syncthreads();
        for (int kk = 0; kk < 32; ++kk) {
            float4 a4 = *(const float4*)&smx[kk * 128 + pl * 4];
            const float* wp = &Whs[kk * 80 + og * 10];
            float2 w0 = *(const float2*)(wp);
            float2 w1 = *(const float2*)(wp + 2);
            float2 w2 = *(const float2*)(wp + 4);
            float2 w3 = *(const float2*)(wp + 6);
            float  w8 = wp[8];
            float wv[9] = {w0.x, w0.y, w1.x, w1.y, w2.x, w2.y, w3.x, w3.y, w8};
            #pragma unroll
            for (int k = 0; k < 9; ++k) {
                float wk = wv[k];
                acc[0][k] += a4.x * wk;
                acc[1][k] += a4.y * wk;
                acc[2][k] += a4.z * wk;
                acc[3][k] += a4.w * wk;
            }
        }
    }

    __syncthreads();
    #pragma unroll
    for (int pi = 0; pi < 4; ++pi)
        #pragma unroll
        for (int k = 0; k < 9; ++k)
            ex[(pl * 4 + pi) * 80 + og * 10 + k] = acc[pi][k];
    __syncthreads();

    if (tid < 128) {
        const int p = p0 + tid;
        float v[72];
        #pragma unroll
        for (int og2 = 0; og2 < 8; ++og2)
            #pragma unroll
            for (int k = 0; k < 9; ++k)
                v[og2 * 9 + k] = ex[tid * 80 + og2 * 10 + k];

        const float im0 = iminfo[b * 3 + 0], im1 = iminfo[b * 3 + 1], im2 = iminfo[b * 3 + 2];
        const float hix = im2 - 1.f, hiy = im1 - 1.f, hiz = im0 - 1.f;
        const int d = p >> 10, h = (p >> 5) & 31, w = p & 31;
        const float sx = w * 8.f, sy = h * 8.f, sz = d * 8.f;

        #pragma unroll 1
        for (int a = 0; a < 9; ++a) {
            float c0 = v[a] + bcls[a];
            float c1 = v[9 + a] + bcls[9 + a];
            float m  = fmaxf(c0, c1);
            float e0 = expf(c0 - m), e1 = expf(c1 - m);
            float sc = e1 / (e0 + e1);
            scores[b * NANCH + p * 9 + a] = sc;
            atomicAdd(&hist[b * 65536 + (__float_as_uint(sc) >> 16)], 1u);

            float aw = (float)(32 << (a % 3));                 // x,y size = 8*SCALES
            float ad = aw * 0.5f * (float)(1 << (a / 3));      // z size = aw*RATIOS
            float ax1 = sx + 3.5f - 0.5f * (aw - 1.f);
            float ax2 = sx + 3.5f + 0.5f * (aw - 1.f);
            float ay1 = sy + 3.5f - 0.5f * (aw - 1.f);
            float ay2 = sy + 3.5f + 0.5f * (aw - 1.f);
            float az1 = sz + 3.5f - 0.5f * (ad - 1.f);
            float az2 = sz + 3.5f + 0.5f * (ad - 1.f);
            float ww_ = ax2 - ax1 + 1.f, hh_ = ay2 - ay1 + 1.f, dd_ = az2 - az1 + 1.f;
            float cx = ax1 + 0.5f * ww_, cy = ay1 + 0.5f * hh_, cz = az1 + 0.5f * dd_;

            const float* dv = &v[18 + a * 6];
            float dx = dv[0] + bbb[a * 6 + 0];
            float dy = dv[1] + bbb[a * 6 + 1];
            float dz = dv[2] + bbb[a * 6 + 2];
            float dw = dv[3] + bbb[a * 6 + 3];
            float dh = dv[4] + bbb[a * 6 + 4];
            float dd2 = dv[5] + bbb[a * 6 + 5];
            float pcx = dx * ww_ + cx, pcy = dy * hh_ + cy, pcz = dz * dd_ + cz;
            float pw = expf(dw) * ww_, ph = expf(dh) * hh_, pd = expf(dd2) * dd_;
            float x1 = fminf(fmaxf(pcx - 0.5f * pw, 0.f), hix);
            float y1 = fminf(fmaxf(pcy - 0.5f * ph, 0.f), hiy);
            float z1 = fminf(fmaxf(pcz - 0.5f * pd, 0.f), hiz);
            float x2 = fminf(fmaxf(pcx + 0.5f * pw, 0.f), hix);
            float y2 = fminf(fmaxf(pcy + 0.5f * ph, 0.f), hiy);
            float z2 = fminf(fmaxf(pcz + 0.5f * pd, 0.f), hiz);
            float* bp = &boxes[(size_t)(b * NANCH + p * 9 + a) * 6];
            bp[0] = x1; bp[1] = y1; bp[2] = z1; bp[3] = x2; bp[4] = y2; bp[5] = z2;
        }
    }
}

// ---------------- fused cutoff + compact (one block per batch) ----------------
__global__ __launch_bounds__(1024) void k_cutcompact(const float* __restrict__ scores,
                                                     const unsigned int* __restrict__ hist,
                                                     unsigned long long* __restrict__ cand) {
    __shared__ unsigned int cs[1024], scan[1024];
    __shared__ unsigned int sh_cut, sh_pos;
    const int b = blockIdx.x, tid = threadIdx.x;
    const unsigned int* h = hist + b * 65536;
    unsigned int s = 0;
    for (int i = 0; i < 64; ++i) s += h[tid * 64 + i];
    cs[tid] = s; scan[tid] = s;
    if (tid == 0) sh_pos = 0;
    __syncthreads();
    for (int d = 1; d < 1024; d <<= 1) {           // scan[c] -> sum_{c'>=c} cs[c']
        unsigned int v = scan[tid];
        unsigned int add = (tid + d < 1024) ? scan[tid + d] : 0u;
        __syncthreads();
        scan[tid] = v + add;
        __syncthreads();
    }
    unsigned int above = (tid + 1 < 1024) ? scan[tid + 1] : 0u;   // strictly above this chunk
    if (above < PRE && above + cs[tid] >= PRE) {   // exactly one thread
        unsigned int cum = above;
        for (int x = tid * 64 + 63; x >= tid * 64; --x) {
            cum += h[x];
            if (cum >= PRE) { sh_cut = (unsigned int)x; break; }
        }
    }
    __syncthreads();
    const unsigned int cut = sh_cut;
    const float* sc = scores + b * NANCH;
    for (int i = tid; i < NANCH; i += 1024) {
        unsigned int u = __float_as_uint(sc[i]);
        if ((u >> 16) >= cut) {
            unsigned int pos = atomicAdd(&sh_pos, 1u);
            if (pos < CAP) cand[b * CAP + pos] = ((unsigned long long)(~u) << 32) | (unsigned)i;
        }
    }
    __syncthreads();
    const unsigned int cnt = (sh_pos < CAP) ? sh_pos : CAP;
    for (int i = (int)cnt + tid; i < CAP; i += 1024)
        cand[b * CAP + i] = ~0ull;
}

// bitonic sort CAP keys asc (key = ~score_bits || idx => score desc, idx asc);
// first 2048 are the sorted top-2048; gather their boxes.
__global__ __launch_bounds__(1024) void k_sort2(const unsigned long long* __restrict__ cand,
                                                const float* __restrict__ boxes,
                                                float* __restrict__ sboxes) {
    __shared__ unsigned long long sk[CAP];
    const int b = blockIdx.x, tid = threadIdx.x;
    for (int i = tid; i < CAP; i += 1024) sk[i] = cand[b * CAP + i];
    __syncthreads();
    for (int k = 2; k <= CAP; k <<= 1) {
        for (int j = k >> 1; j > 0; j >>= 1) {
            #pragma unroll 1
            for (int i = tid; i < CAP; i += 1024) {
                int ixj = i ^ j;
                if (ixj > i) {
                    unsigned long long va = sk[i], vb = sk[ixj];
                    bool up = ((i & k) == 0);
                    if ((va > vb) == up) { sk[i] = vb; sk[ixj] = va; }
                }
            }
            __syncthreads();
        }
    }
    for (int r = tid; r < PRE; r += 1024) {
        unsigned int n = (unsigned int)(sk[r] & 0xFFFFFFFFull);
        const float* src = &boxes[(size_t)(b * NANCH + (int)n) * 6];
        float* dst = &sboxes[(size_t)(b * PRE + r) * 6];
        #pragma unroll
        for (int c = 0; c < 6; ++c) dst[c] = src[c];
    }
}

// suppression bitmask (upper triangle only): mask[b][i][w] bit j <=> j>i && IoU>0.7
__global__ __launch_bounds__(256) void k_mask(const float* __restrict__ sboxes,
                                              unsigned long long* __restrict__ mask) {
    if (blockIdx.y < blockIdx.x) return;   // j0 < i0: never read (k_nms gates by word)
    __shared__ float rb[64 * 6], cb[64 * 6];
    const int i0 = blockIdx.x * 64, j0 = blockIdx.y * 64, b = blockIdx.z;
    const int tid = threadIdx.x;
    for (int e = tid; e < 384; e += 256) {
        rb[e] = sboxes[(size_t)(b * PRE + i0) * 6 + e];
        cb[e] = sboxes[(size_t)(b * PRE + j0) * 6 + e];
    }
    __syncthreads();
    const int wave = tid >> 6, lane = tid & 63;
    const float bx1 = cb[lane * 6 + 0], by1 = cb[lane * 6 + 1], bz1 = cb[lane * 6 + 2];
    const float bx2 = cb[lane * 6 + 3], by2 = cb[lane * 6 + 4], bz2 = cb[lane * 6 + 5];
    const float vb = (bx2 - bx1 + 1.f) * (by2 - by1 + 1.f) * (bz2 - bz1 + 1.f);
    const int j = j0 + lane;
    for (int rr = 0; rr < 16; ++rr) {
        const int il = wave * 16 + rr;
        const int i = i0 + il;
        float ax1 = rb[il * 6 + 0], ay1 = rb[il * 6 + 1], az1 = rb[il * 6 + 2];
        float ax2 = rb[il * 6 + 3], ay2 = rb[il * 6 + 4], az2 = rb[il * 6 + 5];
        float va = (ax2 - ax1 + 1.f) * (ay2 - ay1 + 1.f) * (az2 - az1 + 1.f);
        float ix = fmaxf(fminf(ax2, bx2) - fmaxf(ax1, bx1) + 1.f, 0.f);
        float iy = fmaxf(fminf(ay2, by2) - fmaxf(ay1, by1) + 1.f, 0.f);
        float iz = fmaxf(fminf(az2, bz2) - fmaxf(az1, bz1) + 1.f, 0.f);
        float inter = ix * iy * iz;
        float iou = inter / (va + vb - inter);
        bool bit = (j > i) && (iou > NMS_TH);
        unsigned long long word = __ballot(bit);
        if (lane == 0) mask[(size_t)(b * PRE + i) * 32 + (j0 >> 6)] = word;
    }
}

// single-wave greedy NMS scan + ROI output; 8-deep mask-row prefetch.
__global__ __launch_bounds__(64) void k_nms(const unsigned long long* __restrict__ mask,
                                            const float* __restrict__ sboxes,
                                            float* __restrict__ out) {
    const int b = blockIdx.x, lane = threadIdx.x;
    __shared__ int sel[POST];
    unsigned long long keep = ~0ull;          // lane l<32 owns bits [64l,64l+64)
    const int lw = lane & 31;
    const unsigned long long* mrow = mask + (size_t)b * PRE * 32 + lw;
    unsigned long long b0 = mrow[0 * 32], b1 = mrow[1 * 32], b2 = mrow[2 * 32], b3 = mrow[3 * 32];
    unsigned long long b4 = mrow[4 * 32], b5 = mrow[5 * 32], b6 = mrow[6 * 32], b7 = mrow[7 * 32];
    int kcount = 0;

#define NMS_STEP(J, BUF)                                                        \
    {                                                                           \
        int i = i0 + (J);                                                       \
        unsigned long long cur = (lw >= (i >> 6)) ? BUF : 0ull;                 \
        int nr = i0 + 8 + (J);                                                  \
        BUF = (nr < PRE) ? mrow[(size_t)nr * 32] : 0ull;                        \
        unsigned long long kw = __shfl(keep, i >> 6);                           \
        if ((kw >> (i & 63)) & 1ull) {                                          \
            if (lane < 32) keep &= ~cur;                                        \
            if (lane == 0 && kcount < POST) sel[kcount] = i;                    \
            ++kcount;                                                           \
            if (kcount >= POST) goto nms_done;                                  \
        }                                                                       \
    }

    for (int i0 = 0; i0 < PRE; i0 += 8) {
        NMS_STEP(0, b0) NMS_STEP(1, b1) NMS_STEP(2, b2) NMS_STEP(3, b3)
        NMS_STEP(4, b4) NMS_STEP(5, b5) NMS_STEP(6, b6) NMS_STEP(7, b7)
    }
nms_done:
    __syncthreads();
    const int kc = kcount;
    for (int r = lane; r < POST; r += 64) {
        float* op = &out[(size_t)(b * POST + r) * 7];
        op[0] = (float)b;
        if (r < kc) {
            const float* sb = &sboxes[(size_t)(b * PRE + sel[r]) * 6];
            #pragma unroll
            for (int c = 0; c < 6; ++c) op[1 + c] = sb[c];
        } else {
            #pragma unroll
            for (int c = 0; c < 6; ++c) op[1 + c] = 0.f;
        }
    }
#undef NMS_STEP
}

extern "C" void kernel_launch(void* const* d_in, const int* in_sizes, int n_in,
                              void* d_out, int out_size, void* d_ws, size_t ws_size,
                              hipStream_t stream) {
    const float* base_feat = (const float*)d_in[0];
    const float* im_info   = (const float*)d_in[1];
    const float* W_conv    = (const float*)d_in[4];
    const float* b_conv    = (const float*)d_in[5];
    const float* W_cls     = (const float*)d_in[6];
    const float* b_cls     = (const float*)d_in[7];
    const float* W_bbox    = (const float*)d_in[8];
    const float* b_bbox    = (const float*)d_in[9];

    char* ws = (char*)d_ws;
    u16* Wg        = (u16*)(ws + OFF_WT);
    float* Wht     = (float*)(ws + OFF_WHT);
    float* x       = (float*)(ws + OFF_X);
    float* scores  = (float*)(ws + OFF_SC);
    float* boxes   = (float*)(ws + OFF_BX);
    float* sboxes  = (float*)(ws + OFF_SB);
    unsigned long long* mask = (unsigned long long*)(ws + OFF_MK);
    unsigned int* hist = (unsigned int*)(ws + OFF_HIST);
    unsigned long long* cand = (unsigned long long*)(ws + OFF_CAND);
    u16* xh        = (u16*)(ws + OFF_XH);
    u16* xl        = (u16*)(ws + OFF_XL);

    const int NTRANS = NT_WT + NT_WHT;
    k_wtrans<<<(NTRANS + 255) / 256, 256, 0, stream>>>(W_conv, Wg, W_cls, W_bbox, Wht);
    k_split<<<512, 256, 0, stream>>>(base_feat, xh, xl);
    k_conv_f<<<dim3(64, 8, 2), 128, 0, stream>>>(xh, xl, Wg, b_conv, x);
    // Wg region dead now; zero hist (aliases Wg) AFTER conv, before k_heads.
    hipMemsetAsync(hist, 0, BATCH * 65536 * sizeof(unsigned int), stream);
    k_heads<<<dim3(64, 2), 256, 0, stream>>>(x, Wht, b_cls, b_bbox, im_info, scores, boxes, hist);
    k_cutcompact<<<BATCH, 1024, 0, stream>>>(scores, hist, cand);
    k_sort2<<<BATCH, 1024, 0, stream>>>(cand, boxes, sboxes);
    k_mask<<<dim3(32, 32, 2), 256, 0, stream>>>(sboxes, mask);
    k_nms<<<BATCH, 64, 0, stream>>>(mask, sboxes, (float*)d_out);
}